// Round 2
// baseline (1905.592 us; speedup 1.0000x reference)
//
#include <hip/hip_runtime.h>

// GraphDA: two 2-layer GAT branches + softmax fusion + classifier.
// Strategy: f32 tiled GEMMs for feature transforms, CSR-by-dst + one wave
// per destination node for the segment-softmax aggregation (no f32 atomics).

static constexpr int D_IN = 512;
static constexpr int H1c  = 128;
static constexpr int H2c  = 64;
static constexpr int NCLS = 10;

#define DEV __device__ __forceinline__

DEV float waveReduceSum(float v) {
#pragma unroll
  for (int off = 32; off; off >>= 1) v += __shfl_xor(v, off);
  return v;
}
DEV float waveReduceMax(float v) {
#pragma unroll
  for (int off = 32; off; off >>= 1) v = fmaxf(v, __shfl_xor(v, off));
  return v;
}

// ---------------- sum of E floats -> out[0] (for self-loop mean attr)
__global__ void k_sum(const float* __restrict__ x, int n, float* __restrict__ out) {
  float v = 0.f;
  for (int i = blockIdx.x * blockDim.x + threadIdx.x; i < n; i += gridDim.x * blockDim.x)
    v += x[i];
  v = waveReduceSum(v);
  if ((threadIdx.x & 63) == 0) atomicAdd(out, v);
}

// ---------------- c1 = dot(We1, ae1) [128], c2 = dot(We2, ae2) [64] -> scal[1], scal[2]
__global__ void k_edge_coef(const float* __restrict__ We1, const float* __restrict__ ae1,
                            const float* __restrict__ We2, const float* __restrict__ ae2,
                            float* __restrict__ scal) {
  int lane = threadIdx.x;
  float p1 = We1[lane] * ae1[lane] + We1[lane + 64] * ae1[lane + 64];
  float p2 = We2[lane] * ae2[lane];
  p1 = waveReduceSum(p1);
  p2 = waveReduceSum(p2);
  if (lane == 0) { scal[1] = p1; scal[2] = p2; }
}

// ---------------- histogram of dst (with implicit self loops)
__global__ void k_count(const int* __restrict__ ei, int E, int n, int* __restrict__ counts) {
  int tot = E + n;
  for (int e = blockIdx.x * blockDim.x + threadIdx.x; e < tot; e += gridDim.x * blockDim.x) {
    int d = (e < E) ? ei[(size_t)E + e] : (e - E);
    atomicAdd(&counts[d], 1);
  }
}

// ---------------- block-wise exclusive scan (3 kernels)
__global__ void k_scan_block(const int* __restrict__ counts, int n,
                             int* __restrict__ rowptr, int* __restrict__ blockSums) {
  __shared__ int buf[256];
  int tid = threadIdx.x;
  int i = blockIdx.x * 256 + tid;
  int v = (i < n) ? counts[i] : 0;
  buf[tid] = v;
  __syncthreads();
#pragma unroll
  for (int off = 1; off < 256; off <<= 1) {
    int t = (tid >= off) ? buf[tid - off] : 0;
    __syncthreads();
    buf[tid] += t;
    __syncthreads();
  }
  if (i < n) rowptr[i] = buf[tid] - v;  // local exclusive
  if (tid == 255) blockSums[blockIdx.x] = buf[255];
}

__global__ void k_scan_sums(int* __restrict__ bs, int nb) {
  __shared__ int buf[256];
  int tid = threadIdx.x;
  int v = (tid < nb) ? bs[tid] : 0;
  buf[tid] = v;
  __syncthreads();
#pragma unroll
  for (int off = 1; off < 256; off <<= 1) {
    int t = (tid >= off) ? buf[tid - off] : 0;
    __syncthreads();
    buf[tid] += t;
    __syncthreads();
  }
  if (tid < nb) bs[tid] = buf[tid] - v;  // exclusive
  if (tid == 255) bs[nb] = buf[255];     // total
}

__global__ void k_scan_add(int* __restrict__ rowptr, const int* __restrict__ bs, int n, int nb) {
  int i = blockIdx.x * blockDim.x + threadIdx.x;
  if (i < n) rowptr[i] += bs[i >> 8];
  else if (i == n) rowptr[n] = bs[nb];
}

// ---------------- scatter edges into CSR slots (src id + optional edge attr)
__global__ void k_fill(const int* __restrict__ ei, int E, int n,
                       const int* __restrict__ rowptr, int* __restrict__ cursor,
                       int* __restrict__ srcs, float* __restrict__ eaOut,
                       const float* __restrict__ eattr, const float* __restrict__ scal) {
  int tot = E + n;
  float meanea = (eaOut != nullptr) ? (scal[0] / (float)E) : 0.f;
  for (int e = blockIdx.x * blockDim.x + threadIdx.x; e < tot; e += gridDim.x * blockDim.x) {
    int s, d;
    float ev;
    if (e < E) {
      s = ei[e];
      d = ei[(size_t)E + e];
      ev = (eaOut != nullptr) ? eattr[e] : 0.f;
    } else {
      s = d = e - E;
      ev = meanea;
    }
    int pos = atomicAdd(&cursor[d], 1);
    int slot = rowptr[d] + pos;
    srcs[slot] = s;
    if (eaOut != nullptr) eaOut[slot] = ev;
  }
}

// ---------------- tiled f32 GEMM: C[M,N] = A[M,K] @ B[K,N] (row-major)
template <int BM, int BN, int BK, int TM, int TN>
__global__ __launch_bounds__(256) void gemm_f32(const float* __restrict__ A,
                                                const float* __restrict__ B,
                                                float* __restrict__ C, int M, int N, int K) {
  __shared__ float As[BM][BK + 1];
  __shared__ float Bs[BK][BN + 1];
  constexpr int TX = BN / TN;
  const int tid = threadIdx.x;
  const int tx = tid % TX;
  const int ty = tid / TX;
  const int rowBase = blockIdx.x * BM;
  const int colBase = blockIdx.y * BN;
  float acc[TM][TN] = {};
  constexpr int AV = BK / 4;    // float4 per A row
  constexpr int AR = 256 / AV;  // A rows per iter
  constexpr int BV = BN / 4;
  constexpr int BR = 256 / BV;
  const int a_r = tid / AV, a_c = (tid % AV) * 4;
  const int b_r = tid / BV, b_c = (tid % BV) * 4;
  for (int k0 = 0; k0 < K; k0 += BK) {
#pragma unroll
    for (int it = 0; it < BM / AR; ++it) {
      int r = it * AR + a_r;
      int gr = rowBase + r;
      float4 v = make_float4(0.f, 0.f, 0.f, 0.f);
      if (gr < M) v = *(const float4*)(A + (size_t)gr * K + k0 + a_c);
      As[r][a_c] = v.x; As[r][a_c + 1] = v.y; As[r][a_c + 2] = v.z; As[r][a_c + 3] = v.w;
    }
#pragma unroll
    for (int it = 0; it < BK / BR; ++it) {
      int r = it * BR + b_r;
      float4 v = *(const float4*)(B + (size_t)(k0 + r) * N + colBase + b_c);
      Bs[r][b_c] = v.x; Bs[r][b_c + 1] = v.y; Bs[r][b_c + 2] = v.z; Bs[r][b_c + 3] = v.w;
    }
    __syncthreads();
#pragma unroll
    for (int kk = 0; kk < BK; ++kk) {
      float a[TM], b[TN];
#pragma unroll
      for (int i = 0; i < TM; ++i) a[i] = As[ty * TM + i][kk];
#pragma unroll
      for (int j = 0; j < TN; ++j) b[j] = Bs[kk][tx * TN + j];
#pragma unroll
      for (int i = 0; i < TM; ++i)
#pragma unroll
        for (int j = 0; j < TN; ++j) acc[i][j] = fmaf(a[i], b[j], acc[i][j]);
    }
    __syncthreads();
  }
#pragma unroll
  for (int i = 0; i < TM; ++i) {
    int gr = rowBase + ty * TM + i;
    if (gr < M) {
      float* cp = C + (size_t)gr * N + colBase + tx * TN;
#pragma unroll
      for (int j = 0; j < TN; ++j) cp[j] = acc[i][j];
    }
  }
}

// ---------------- per-node dots with att_src/att_dst: one wave per node
template <int DIM>
__global__ void k_node_dots(const float* __restrict__ h, const float* __restrict__ va,
                            const float* __restrict__ vb, float* __restrict__ outa,
                            float* __restrict__ outb, int n) {
  int wid = (blockIdx.x * blockDim.x + threadIdx.x) >> 6;
  int lane = threadIdx.x & 63;
  if (wid >= n) return;
  const float* hr = h + (size_t)wid * DIM;
  float pa = 0.f, pb = 0.f;
#pragma unroll
  for (int v = 0; v < DIM / 64; ++v) {
    float xv = hr[lane + 64 * v];
    pa += xv * va[lane + 64 * v];
    pb += xv * vb[lane + 64 * v];
  }
  pa = waveReduceSum(pa);
  pb = waveReduceSum(pb);
  if (lane == 0) { outa[wid] = pa; outb[wid] = pb; }
}

// ---------------- GAT aggregation: one wave per dst node, 2-pass softmax
template <int DIM, bool HAS_EDGE>
__global__ void k_gat_agg(const float* __restrict__ h, const int* __restrict__ rowptr,
                          const int* __restrict__ srcs, const float* __restrict__ ea,
                          const float* __restrict__ scal, int scal_idx,
                          const float* __restrict__ as_, const float* __restrict__ ad_,
                          const float* __restrict__ bias, const float* __restrict__ pa_ptr,
                          float* __restrict__ out, int n) {
  int wid = (blockIdx.x * blockDim.x + threadIdx.x) >> 6;
  int lane = threadIdx.x & 63;
  if (wid >= n) return;
  int e0 = rowptr[wid], e1 = rowptr[wid + 1];
  float adv = ad_[wid];
  float c = HAS_EDGE ? scal[scal_idx] : 0.f;
  // pass 1: max over incoming edges (lane-parallel)
  float m = -INFINITY;
  for (int e = e0 + lane; e < e1; e += 64) {
    float a = as_[srcs[e]] + adv;
    if (HAS_EDGE) a += c * ea[e];
    a = a > 0.f ? a : 0.2f * a;
    m = fmaxf(m, a);
  }
  m = waveReduceMax(m);
  // pass 2: exp-weights + feature accumulation (edge-serial, dim-parallel)
  float ssum = 0.f;
  if constexpr (DIM == 128) {
    float2 acc = make_float2(0.f, 0.f);
    for (int e = e0; e < e1; ++e) {
      int s = srcs[e];
      float a = as_[s] + adv;
      if (HAS_EDGE) a += c * ea[e];
      a = a > 0.f ? a : 0.2f * a;
      float w = __expf(a - m);
      ssum += w;
      float2 hv = ((const float2*)(h + (size_t)s * 128))[lane];
      acc.x += w * hv.x;
      acc.y += w * hv.y;
    }
    float inv = 1.f / (ssum + 1e-16f);
    float pa = pa_ptr[0];
    float2 bv = ((const float2*)bias)[lane];
    float ox = acc.x * inv + bv.x;
    float oy = acc.y * inv + bv.y;
    ox = ox >= 0.f ? ox : pa * ox;
    oy = oy >= 0.f ? oy : pa * oy;
    ((float2*)(out + (size_t)wid * 128))[lane] = make_float2(ox, oy);
  } else {
    float acc = 0.f;
    for (int e = e0; e < e1; ++e) {
      int s = srcs[e];
      float a = as_[s] + adv;
      if (HAS_EDGE) a += c * ea[e];
      a = a > 0.f ? a : 0.2f * a;
      float w = __expf(a - m);
      ssum += w;
      acc += w * h[(size_t)s * 64 + lane];
    }
    float inv = 1.f / (ssum + 1e-16f);
    float pa = pa_ptr[0];
    float o = acc * inv + bias[lane];
    o = o >= 0.f ? o : pa * o;
    out[(size_t)wid * 64 + lane] = o;
  }
}

// ---------------- fusion softmax + classifier: one wave per node
__global__ void k_fuse(const float* __restrict__ lout, const float* __restrict__ gout,
                       const float* __restrict__ attn_w, const float* __restrict__ attn_b,
                       const float* __restrict__ clf_w, const float* __restrict__ clf_b,
                       float* __restrict__ out, int n) {
  int wid = (blockIdx.x * blockDim.x + threadIdx.x) >> 6;
  int lane = threadIdx.x & 63;
  if (wid >= n) return;
  float l = lout[(size_t)wid * 64 + lane];
  float g = gout[(size_t)wid * 64 + lane];
  float aw = attn_w[lane];
  float s0 = waveReduceSum(l * aw) + attn_b[0];
  float s1 = waveReduceSum(g * aw) + attn_b[0];
  float mx = fmaxf(s0, s1);
  float e0 = __expf(s0 - mx), e1 = __expf(s1 - mx);
  float inv = 1.f / (e0 + e1);
  float w0 = e0 * inv, w1 = e1 * inv;
  float emb = w0 * l + w1 * g;
  out[(size_t)wid * 64 + lane] = emb;
  float p[NCLS];
#pragma unroll
  for (int cc = 0; cc < NCLS; ++cc) p[cc] = emb * clf_w[lane * NCLS + cc];
#pragma unroll
  for (int off = 32; off; off >>= 1)
#pragma unroll
    for (int cc = 0; cc < NCLS; ++cc) p[cc] += __shfl_xor(p[cc], off);
  if (lane < NCLS) {
    float val = 0.f;
#pragma unroll
    for (int cc = 0; cc < NCLS; ++cc)
      if (lane == cc) val = p[cc];
    out[(size_t)n * 64 + (size_t)wid * NCLS + lane] = val + clf_b[lane];
  }
}

extern "C" void kernel_launch(void* const* d_in, const int* in_sizes, int n_in,
                              void* d_out, int out_size, void* d_ws, size_t ws_size,
                              hipStream_t stream) {
  const float* x         = (const float*)d_in[0];
  const int*   ei        = (const int*)d_in[1];
  const int*   pei       = (const int*)d_in[2];
  const float* pea       = (const float*)d_in[3];
  const float* W1        = (const float*)d_in[4];
  const float* att_src1  = (const float*)d_in[5];
  const float* att_dst1  = (const float*)d_in[6];
  const float* b1        = (const float*)d_in[7];
  const float* W2        = (const float*)d_in[8];
  const float* att_src2  = (const float*)d_in[9];
  const float* att_dst2  = (const float*)d_in[10];
  const float* b2        = (const float*)d_in[11];
  const float* prelu_a   = (const float*)d_in[12];
  const float* pW1       = (const float*)d_in[13];
  const float* patt_src1 = (const float*)d_in[14];
  const float* patt_dst1 = (const float*)d_in[15];
  const float* pWe1      = (const float*)d_in[16];
  const float* patt_e1   = (const float*)d_in[17];
  const float* pb1       = (const float*)d_in[18];
  const float* pW2       = (const float*)d_in[19];
  const float* patt_src2 = (const float*)d_in[20];
  const float* patt_dst2 = (const float*)d_in[21];
  const float* pWe2      = (const float*)d_in[22];
  const float* patt_e2   = (const float*)d_in[23];
  const float* pb2       = (const float*)d_in[24];
  const float* pprelu_a  = (const float*)d_in[25];
  const float* attn_w    = (const float*)d_in[26];
  const float* attn_b    = (const float*)d_in[27];
  const float* clf_w     = (const float*)d_in[28];
  const float* clf_b     = (const float*)d_in[29];
  float* out = (float*)d_out;

  const int N = in_sizes[0] / D_IN;
  const int E = in_sizes[1] / 2;
  const int Etot = E + N;

  // ---- workspace layout (floats, then ints)
  float* wf = (float*)d_ws;
  size_t o = 0;
  float* h1a = wf + o; o += (size_t)N * H1c;
  float* h1p = wf + o; o += (size_t)N * H1c;
  float* f1a = wf + o; o += (size_t)N * H1c;
  float* g1p = wf + o; o += (size_t)N * H1c;
  float* eaP = wf + o; o += (size_t)Etot;
  float* as_a = wf + o; o += N;
  float* ad_a = wf + o; o += N;
  float* as_p = wf + o; o += N;
  float* ad_p = wf + o; o += N;
  float* scal = wf + o; o += 8;  // [0]=sum(pea), [1]=c1, [2]=c2
  // reuse layer-1 h buffers for layer-2 tensors:
  float* h2a   = h1a;                    // N*H2
  float* l_out = h1a + (size_t)N * H2c;  // N*H2
  float* h2p   = h1p;
  float* g_out = h1p + (size_t)N * H2c;

  int* wi = (int*)(wf + o);
  int* rowptrA = wi;
  int* rowptrP = rowptrA + (N + 1);
  int* zeroReg = rowptrP + (N + 1);
  int* countsA = zeroReg;
  int* countsP = countsA + N;
  int* cursA   = countsP + N;
  int* cursP   = cursA + N;
  int* blockSums = cursP + N;  // 512 ints
  int* srcsA = blockSums + 512;
  int* srcsP = srcsA + Etot;
  size_t needBytes = (size_t)((char*)(srcsP + Etot) - (char*)d_ws);
  if (needBytes > ws_size) return;  // would corrupt; fail loudly (output stays zero)

  hipMemsetAsync(zeroReg, 0, sizeof(int) * (size_t)4 * N, stream);
  hipMemsetAsync(scal, 0, sizeof(float) * 8, stream);

  const int GS = 2048;
  // self-loop mean attr + edge coefficient scalars
  k_sum<<<1024, 256, 0, stream>>>(pea, E, scal);
  k_edge_coef<<<1, 64, 0, stream>>>(pWe1, patt_e1, pWe2, patt_e2, scal);

  // CSR build for both graphs
  k_count<<<GS, 256, 0, stream>>>(ei, E, N, countsA);
  k_count<<<GS, 256, 0, stream>>>(pei, E, N, countsP);
  int nb = (N + 255) / 256;
  int scanAddBlocks = (N + 1 + 255) / 256;
  k_scan_block<<<nb, 256, 0, stream>>>(countsA, N, rowptrA, blockSums);
  k_scan_sums<<<1, 256, 0, stream>>>(blockSums, nb);
  k_scan_add<<<scanAddBlocks, 256, 0, stream>>>(rowptrA, blockSums, N, nb);
  k_scan_block<<<nb, 256, 0, stream>>>(countsP, N, rowptrP, blockSums);
  k_scan_sums<<<1, 256, 0, stream>>>(blockSums, nb);
  k_scan_add<<<scanAddBlocks, 256, 0, stream>>>(rowptrP, blockSums, N, nb);
  k_fill<<<GS, 256, 0, stream>>>(ei, E, N, rowptrA, cursA, srcsA, nullptr, nullptr, scal);
  k_fill<<<GS, 256, 0, stream>>>(pei, E, N, rowptrP, cursP, srcsP, eaP, pea, scal);

  // layer 1: h = x @ W (both branches), att dots, aggregation (+bias +prelu)
  dim3 g1((N + 63) / 64, H1c / 128);
  gemm_f32<64, 128, 32, 4, 8><<<g1, 256, 0, stream>>>(x, W1, h1a, N, H1c, D_IN);
  gemm_f32<64, 128, 32, 4, 8><<<g1, 256, 0, stream>>>(x, pW1, h1p, N, H1c, D_IN);
  int gw = (N + 3) / 4;  // 4 waves per block, 1 node per wave
  k_node_dots<H1c><<<gw, 256, 0, stream>>>(h1a, att_src1, att_dst1, as_a, ad_a, N);
  k_node_dots<H1c><<<gw, 256, 0, stream>>>(h1p, patt_src1, patt_dst1, as_p, ad_p, N);
  k_gat_agg<H1c, false><<<gw, 256, 0, stream>>>(h1a, rowptrA, srcsA, nullptr, scal, 0,
                                                as_a, ad_a, b1, prelu_a, f1a, N);
  k_gat_agg<H1c, true><<<gw, 256, 0, stream>>>(h1p, rowptrP, srcsP, eaP, scal, 1,
                                               as_p, ad_p, pb1, pprelu_a, g1p, N);

  // layer 2
  dim3 g2((N + 63) / 64, H2c / 64);
  gemm_f32<64, 64, 32, 4, 4><<<g2, 256, 0, stream>>>(f1a, W2, h2a, N, H2c, H1c);
  gemm_f32<64, 64, 32, 4, 4><<<g2, 256, 0, stream>>>(g1p, pW2, h2p, N, H2c, H1c);
  k_node_dots<H2c><<<gw, 256, 0, stream>>>(h2a, att_src2, att_dst2, as_a, ad_a, N);
  k_node_dots<H2c><<<gw, 256, 0, stream>>>(h2p, patt_src2, patt_dst2, as_p, ad_p, N);
  k_gat_agg<H2c, false><<<gw, 256, 0, stream>>>(h2a, rowptrA, srcsA, nullptr, scal, 0,
                                                as_a, ad_a, b2, prelu_a, l_out, N);
  k_gat_agg<H2c, true><<<gw, 256, 0, stream>>>(h2p, rowptrP, srcsP, eaP, scal, 2,
                                               as_p, ad_p, pb2, pprelu_a, g_out, N);

  // fusion + classifier
  k_fuse<<<gw, 256, 0, stream>>>(l_out, g_out, attn_w, attn_b, clf_w, clf_b, out, N);
}

// Round 3
// 1264.289 us; speedup vs baseline: 1.5072x; 1.5072x over previous
//
#include <hip/hip_runtime.h>

// GraphDA: two 2-layer GAT branches + softmax fusion + classifier.
// f32 GEMMs with transposed-A LDS tiles (vectorized ds_read_b128),
// CSR-by-dst + one wave per dst node for segment softmax (no f32 atomics),
// aggregation edge loop unrolled x4 for memory-level parallelism.

static constexpr int D_IN = 512;
static constexpr int H1c  = 128;
static constexpr int H2c  = 64;
static constexpr int NCLS = 10;

#define DEV __device__ __forceinline__

DEV float waveReduceSum(float v) {
#pragma unroll
  for (int off = 32; off; off >>= 1) v += __shfl_xor(v, off);
  return v;
}
DEV float waveReduceMax(float v) {
#pragma unroll
  for (int off = 32; off; off >>= 1) v = fmaxf(v, __shfl_xor(v, off));
  return v;
}

// ---------------- sum of E floats -> out[0] (for self-loop mean attr)
__global__ void k_sum(const float* __restrict__ x, int n, float* __restrict__ out) {
  float v = 0.f;
  for (int i = blockIdx.x * blockDim.x + threadIdx.x; i < n; i += gridDim.x * blockDim.x)
    v += x[i];
  v = waveReduceSum(v);
  if ((threadIdx.x & 63) == 0) atomicAdd(out, v);
}

// ---------------- c1 = dot(We1, ae1) [128], c2 = dot(We2, ae2) [64]
__global__ void k_edge_coef(const float* __restrict__ We1, const float* __restrict__ ae1,
                            const float* __restrict__ We2, const float* __restrict__ ae2,
                            float* __restrict__ scal) {
  int lane = threadIdx.x;
  float p1 = We1[lane] * ae1[lane] + We1[lane + 64] * ae1[lane + 64];
  float p2 = We2[lane] * ae2[lane];
  p1 = waveReduceSum(p1);
  p2 = waveReduceSum(p2);
  if (lane == 0) { scal[1] = p1; scal[2] = p2; }
}

// ---------------- histogram of dst (with implicit self loops)
__global__ void k_count(const int* __restrict__ ei, int E, int n, int* __restrict__ counts) {
  int tot = E + n;
  for (int e = blockIdx.x * blockDim.x + threadIdx.x; e < tot; e += gridDim.x * blockDim.x) {
    int d = (e < E) ? ei[(size_t)E + e] : (e - E);
    atomicAdd(&counts[d], 1);
  }
}

// ---------------- block-wise exclusive scan (3 kernels)
__global__ void k_scan_block(const int* __restrict__ counts, int n,
                             int* __restrict__ rowptr, int* __restrict__ blockSums) {
  __shared__ int buf[256];
  int tid = threadIdx.x;
  int i = blockIdx.x * 256 + tid;
  int v = (i < n) ? counts[i] : 0;
  buf[tid] = v;
  __syncthreads();
#pragma unroll
  for (int off = 1; off < 256; off <<= 1) {
    int t = (tid >= off) ? buf[tid - off] : 0;
    __syncthreads();
    buf[tid] += t;
    __syncthreads();
  }
  if (i < n) rowptr[i] = buf[tid] - v;  // local exclusive
  if (tid == 255) blockSums[blockIdx.x] = buf[255];
}

__global__ void k_scan_sums(int* __restrict__ bs, int nb) {
  __shared__ int buf[256];
  int tid = threadIdx.x;
  int v = (tid < nb) ? bs[tid] : 0;
  buf[tid] = v;
  __syncthreads();
#pragma unroll
  for (int off = 1; off < 256; off <<= 1) {
    int t = (tid >= off) ? buf[tid - off] : 0;
    __syncthreads();
    buf[tid] += t;
    __syncthreads();
  }
  if (tid < nb) bs[tid] = buf[tid] - v;  // exclusive
  if (tid == 255) bs[nb] = buf[255];     // total
}

__global__ void k_scan_add(int* __restrict__ rowptr, const int* __restrict__ bs, int n, int nb) {
  int i = blockIdx.x * blockDim.x + threadIdx.x;
  if (i < n) rowptr[i] += bs[i >> 8];
  else if (i == n) rowptr[n] = bs[nb];
}

// ---------------- scatter edges into CSR slots (src id + optional edge attr)
__global__ void k_fill(const int* __restrict__ ei, int E, int n,
                       const int* __restrict__ rowptr, int* __restrict__ cursor,
                       int* __restrict__ srcs, float* __restrict__ eaOut,
                       const float* __restrict__ eattr, const float* __restrict__ scal) {
  int tot = E + n;
  float meanea = (eaOut != nullptr) ? (scal[0] / (float)E) : 0.f;
  for (int e = blockIdx.x * blockDim.x + threadIdx.x; e < tot; e += gridDim.x * blockDim.x) {
    int s, d;
    float ev;
    if (e < E) {
      s = ei[e];
      d = ei[(size_t)E + e];
      ev = (eaOut != nullptr) ? eattr[e] : 0.f;
    } else {
      s = d = e - E;
      ev = meanea;
    }
    int pos = atomicAdd(&cursor[d], 1);
    int slot = rowptr[d] + pos;
    srcs[slot] = s;
    if (eaOut != nullptr) eaOut[slot] = ev;
  }
}

// ---------------- tiled f32 GEMM, A-tile stored TRANSPOSED in LDS so all
// fragment reads are ds_read_b128. C[M,N] = A[M,K] @ B[K,N], row-major.
template <int BM, int BN, int BK, int TM, int TN>
__global__ __launch_bounds__(256) void gemm_f32t(const float* __restrict__ A,
                                                 const float* __restrict__ B,
                                                 float* __restrict__ C, int M, int N, int K) {
  __shared__ float As[BK][BM + 4];  // transposed: As[k][m]
  __shared__ float Bs[BK][BN + 4];
  constexpr int TX = BN / TN;
  const int tid = threadIdx.x;
  const int tx = tid % TX;
  const int ty = tid / TX;
  const int rowBase = blockIdx.x * BM;
  const int colBase = blockIdx.y * BN;
  float acc[TM][TN] = {};
  constexpr int A4 = (BM * BK / 4) / 256;  // float4 loads per thread (A)
  constexpr int B4 = (BN * BK / 4) / 256;  // float4 loads per thread (B)
  for (int k0 = 0; k0 < K; k0 += BK) {
#pragma unroll
    for (int it = 0; it < A4; ++it) {
      int idx = it * 256 + tid;
      int row = idx / (BK / 4);
      int cv = (idx % (BK / 4)) * 4;
      int gr = rowBase + row;
      float4 v = make_float4(0.f, 0.f, 0.f, 0.f);
      if (gr < M) v = *(const float4*)(A + (size_t)gr * K + k0 + cv);
      As[cv + 0][row] = v.x;
      As[cv + 1][row] = v.y;
      As[cv + 2][row] = v.z;
      As[cv + 3][row] = v.w;
    }
#pragma unroll
    for (int it = 0; it < B4; ++it) {
      int idx = it * 256 + tid;
      int r = idx / (BN / 4);
      int c = (idx % (BN / 4)) * 4;
      *(float4*)&Bs[r][c] = *(const float4*)(B + (size_t)(k0 + r) * N + colBase + c);
    }
    __syncthreads();
#pragma unroll
    for (int kk = 0; kk < BK; ++kk) {
      float a[TM], b[TN];
#pragma unroll
      for (int i = 0; i < TM; i += 4) *(float4*)&a[i] = *(const float4*)&As[kk][ty * TM + i];
#pragma unroll
      for (int j = 0; j < TN; j += 4) *(float4*)&b[j] = *(const float4*)&Bs[kk][tx * TN + j];
#pragma unroll
      for (int i = 0; i < TM; ++i)
#pragma unroll
        for (int j = 0; j < TN; ++j) acc[i][j] = fmaf(a[i], b[j], acc[i][j]);
    }
    __syncthreads();
  }
#pragma unroll
  for (int i = 0; i < TM; ++i) {
    int gr = rowBase + ty * TM + i;
    if (gr < M) {
      float* cp = C + (size_t)gr * N + colBase + tx * TN;
#pragma unroll
      for (int j = 0; j < TN; j += 4) *(float4*)&cp[j] = *(const float4*)&acc[i][j];
    }
  }
}

// ---------------- per-node dots with att_src/att_dst: one wave per node
template <int DIM>
__global__ void k_node_dots(const float* __restrict__ h, const float* __restrict__ va,
                            const float* __restrict__ vb, float* __restrict__ outa,
                            float* __restrict__ outb, int n) {
  int wid = (blockIdx.x * blockDim.x + threadIdx.x) >> 6;
  int lane = threadIdx.x & 63;
  if (wid >= n) return;
  const float* hr = h + (size_t)wid * DIM;
  float pa = 0.f, pb = 0.f;
#pragma unroll
  for (int v = 0; v < DIM / 64; ++v) {
    float xv = hr[lane + 64 * v];
    pa += xv * va[lane + 64 * v];
    pb += xv * vb[lane + 64 * v];
  }
  pa = waveReduceSum(pa);
  pb = waveReduceSum(pb);
  if (lane == 0) { outa[wid] = pa; outb[wid] = pb; }
}

DEV float leaky02(float a) { return a > 0.f ? a : 0.2f * a; }

// ---------------- GAT aggregation: one wave per dst node, 2-pass softmax.
// Pass 2 unrolled x4: independent gathers issued together (4x MLP).
template <int DIM, bool HAS_EDGE>
__global__ void k_gat_agg(const float* __restrict__ h, const int* __restrict__ rowptr,
                          const int* __restrict__ srcs, const float* __restrict__ ea,
                          const float* __restrict__ scal, int scal_idx,
                          const float* __restrict__ as_, const float* __restrict__ ad_,
                          const float* __restrict__ bias, const float* __restrict__ pa_ptr,
                          float* __restrict__ out, int n) {
  int wid = (blockIdx.x * blockDim.x + threadIdx.x) >> 6;
  int lane = threadIdx.x & 63;
  if (wid >= n) return;
  int e0 = rowptr[wid], e1 = rowptr[wid + 1];
  float adv = ad_[wid];
  float c = HAS_EDGE ? scal[scal_idx] : 0.f;
  // pass 1: max over incoming edges (lane-parallel)
  float m = -INFINITY;
  for (int e = e0 + lane; e < e1; e += 64) {
    float a = as_[srcs[e]] + adv;
    if (HAS_EDGE) a += c * ea[e];
    m = fmaxf(m, leaky02(a));
  }
  m = waveReduceMax(m);
  float pa = pa_ptr[0];
  // pass 2: exp-weights + feature accumulation (edge-serial, dim-parallel)
  float ssum = 0.f;
  if constexpr (DIM == 128) {
    float2 acc = make_float2(0.f, 0.f);
    int e = e0;
    for (; e + 4 <= e1; e += 4) {
      int s0 = srcs[e], s1 = srcs[e + 1], s2 = srcs[e + 2], s3 = srcs[e + 3];
      float a0 = as_[s0], a1 = as_[s1], a2 = as_[s2], a3 = as_[s3];
      float2 h0 = ((const float2*)(h + (size_t)s0 * 128))[lane];
      float2 h1 = ((const float2*)(h + (size_t)s1 * 128))[lane];
      float2 h2 = ((const float2*)(h + (size_t)s2 * 128))[lane];
      float2 h3 = ((const float2*)(h + (size_t)s3 * 128))[lane];
      a0 += adv; a1 += adv; a2 += adv; a3 += adv;
      if (HAS_EDGE) {
        a0 += c * ea[e]; a1 += c * ea[e + 1]; a2 += c * ea[e + 2]; a3 += c * ea[e + 3];
      }
      float w0 = __expf(leaky02(a0) - m), w1 = __expf(leaky02(a1) - m);
      float w2 = __expf(leaky02(a2) - m), w3 = __expf(leaky02(a3) - m);
      ssum += (w0 + w1) + (w2 + w3);
      acc.x += w0 * h0.x + w1 * h1.x + w2 * h2.x + w3 * h3.x;
      acc.y += w0 * h0.y + w1 * h1.y + w2 * h2.y + w3 * h3.y;
    }
    for (; e < e1; ++e) {
      int s = srcs[e];
      float a = as_[s] + adv;
      if (HAS_EDGE) a += c * ea[e];
      float w = __expf(leaky02(a) - m);
      ssum += w;
      float2 hv = ((const float2*)(h + (size_t)s * 128))[lane];
      acc.x += w * hv.x;
      acc.y += w * hv.y;
    }
    float inv = 1.f / (ssum + 1e-16f);
    float2 bv = ((const float2*)bias)[lane];
    float ox = acc.x * inv + bv.x;
    float oy = acc.y * inv + bv.y;
    ox = ox >= 0.f ? ox : pa * ox;
    oy = oy >= 0.f ? oy : pa * oy;
    ((float2*)(out + (size_t)wid * 128))[lane] = make_float2(ox, oy);
  } else {
    float acc = 0.f;
    int e = e0;
    for (; e + 4 <= e1; e += 4) {
      int s0 = srcs[e], s1 = srcs[e + 1], s2 = srcs[e + 2], s3 = srcs[e + 3];
      float a0 = as_[s0], a1 = as_[s1], a2 = as_[s2], a3 = as_[s3];
      float h0 = h[(size_t)s0 * 64 + lane];
      float h1 = h[(size_t)s1 * 64 + lane];
      float h2 = h[(size_t)s2 * 64 + lane];
      float h3 = h[(size_t)s3 * 64 + lane];
      a0 += adv; a1 += adv; a2 += adv; a3 += adv;
      if (HAS_EDGE) {
        a0 += c * ea[e]; a1 += c * ea[e + 1]; a2 += c * ea[e + 2]; a3 += c * ea[e + 3];
      }
      float w0 = __expf(leaky02(a0) - m), w1 = __expf(leaky02(a1) - m);
      float w2 = __expf(leaky02(a2) - m), w3 = __expf(leaky02(a3) - m);
      ssum += (w0 + w1) + (w2 + w3);
      acc += w0 * h0 + w1 * h1 + w2 * h2 + w3 * h3;
    }
    for (; e < e1; ++e) {
      int s = srcs[e];
      float a = as_[s] + adv;
      if (HAS_EDGE) a += c * ea[e];
      float w = __expf(leaky02(a) - m);
      ssum += w;
      acc += w * h[(size_t)s * 64 + lane];
    }
    float inv = 1.f / (ssum + 1e-16f);
    float o = acc * inv + bias[lane];
    o = o >= 0.f ? o : pa * o;
    out[(size_t)wid * 64 + lane] = o;
  }
}

// ---------------- fusion softmax + classifier: one wave per node
__global__ void k_fuse(const float* __restrict__ lout, const float* __restrict__ gout,
                       const float* __restrict__ attn_w, const float* __restrict__ attn_b,
                       const float* __restrict__ clf_w, const float* __restrict__ clf_b,
                       float* __restrict__ out, int n) {
  int wid = (blockIdx.x * blockDim.x + threadIdx.x) >> 6;
  int lane = threadIdx.x & 63;
  if (wid >= n) return;
  float l = lout[(size_t)wid * 64 + lane];
  float g = gout[(size_t)wid * 64 + lane];
  float aw = attn_w[lane];
  float s0 = waveReduceSum(l * aw) + attn_b[0];
  float s1 = waveReduceSum(g * aw) + attn_b[0];
  float mx = fmaxf(s0, s1);
  float e0 = __expf(s0 - mx), e1 = __expf(s1 - mx);
  float inv = 1.f / (e0 + e1);
  float w0 = e0 * inv, w1 = e1 * inv;
  float emb = w0 * l + w1 * g;
  out[(size_t)wid * 64 + lane] = emb;
  float p[NCLS];
#pragma unroll
  for (int cc = 0; cc < NCLS; ++cc) p[cc] = emb * clf_w[lane * NCLS + cc];
#pragma unroll
  for (int off = 32; off; off >>= 1)
#pragma unroll
    for (int cc = 0; cc < NCLS; ++cc) p[cc] += __shfl_xor(p[cc], off);
  if (lane < NCLS) {
    float val = 0.f;
#pragma unroll
    for (int cc = 0; cc < NCLS; ++cc)
      if (lane == cc) val = p[cc];
    out[(size_t)n * 64 + (size_t)wid * NCLS + lane] = val + clf_b[lane];
  }
}

extern "C" void kernel_launch(void* const* d_in, const int* in_sizes, int n_in,
                              void* d_out, int out_size, void* d_ws, size_t ws_size,
                              hipStream_t stream) {
  const float* x         = (const float*)d_in[0];
  const int*   ei        = (const int*)d_in[1];
  const int*   pei       = (const int*)d_in[2];
  const float* pea       = (const float*)d_in[3];
  const float* W1        = (const float*)d_in[4];
  const float* att_src1  = (const float*)d_in[5];
  const float* att_dst1  = (const float*)d_in[6];
  const float* b1        = (const float*)d_in[7];
  const float* W2        = (const float*)d_in[8];
  const float* att_src2  = (const float*)d_in[9];
  const float* att_dst2  = (const float*)d_in[10];
  const float* b2        = (const float*)d_in[11];
  const float* prelu_a   = (const float*)d_in[12];
  const float* pW1       = (const float*)d_in[13];
  const float* patt_src1 = (const float*)d_in[14];
  const float* patt_dst1 = (const float*)d_in[15];
  const float* pWe1      = (const float*)d_in[16];
  const float* patt_e1   = (const float*)d_in[17];
  const float* pb1       = (const float*)d_in[18];
  const float* pW2       = (const float*)d_in[19];
  const float* patt_src2 = (const float*)d_in[20];
  const float* patt_dst2 = (const float*)d_in[21];
  const float* pWe2      = (const float*)d_in[22];
  const float* patt_e2   = (const float*)d_in[23];
  const float* pb2       = (const float*)d_in[24];
  const float* pprelu_a  = (const float*)d_in[25];
  const float* attn_w    = (const float*)d_in[26];
  const float* attn_b    = (const float*)d_in[27];
  const float* clf_w     = (const float*)d_in[28];
  const float* clf_b     = (const float*)d_in[29];
  float* out = (float*)d_out;

  const int N = in_sizes[0] / D_IN;
  const int E = in_sizes[1] / 2;
  const int Etot = E + N;

  // ---- workspace layout (floats, then ints)
  float* wf = (float*)d_ws;
  size_t o = 0;
  float* h1a = wf + o; o += (size_t)N * H1c;
  float* h1p = wf + o; o += (size_t)N * H1c;
  float* f1a = wf + o; o += (size_t)N * H1c;
  float* g1p = wf + o; o += (size_t)N * H1c;
  float* eaP = wf + o; o += (size_t)Etot;
  float* as_a = wf + o; o += N;
  float* ad_a = wf + o; o += N;
  float* as_p = wf + o; o += N;
  float* ad_p = wf + o; o += N;
  float* scal = wf + o; o += 8;  // [0]=sum(pea), [1]=c1, [2]=c2
  // reuse layer-1 h buffers for layer-2 tensors:
  float* h2a   = h1a;                    // N*H2
  float* l_out = h1a + (size_t)N * H2c;  // N*H2
  float* h2p   = h1p;
  float* g_out = h1p + (size_t)N * H2c;

  int* wi = (int*)(wf + o);
  int* rowptrA = wi;
  int* rowptrP = rowptrA + (N + 1);
  int* zeroReg = rowptrP + (N + 1);
  int* countsA = zeroReg;
  int* countsP = countsA + N;
  int* cursA   = countsP + N;
  int* cursP   = cursA + N;
  int* blockSums = cursP + N;  // 512 ints
  int* srcsA = blockSums + 512;
  int* srcsP = srcsA + Etot;
  size_t needBytes = (size_t)((char*)(srcsP + Etot) - (char*)d_ws);
  if (needBytes > ws_size) return;  // would corrupt; fail loudly (output stays zero)

  hipMemsetAsync(zeroReg, 0, sizeof(int) * (size_t)4 * N, stream);
  hipMemsetAsync(scal, 0, sizeof(float) * 8, stream);

  const int GS = 2048;
  // self-loop mean attr + edge coefficient scalars
  k_sum<<<1024, 256, 0, stream>>>(pea, E, scal);
  k_edge_coef<<<1, 64, 0, stream>>>(pWe1, patt_e1, pWe2, patt_e2, scal);

  // CSR build for both graphs
  k_count<<<GS, 256, 0, stream>>>(ei, E, N, countsA);
  k_count<<<GS, 256, 0, stream>>>(pei, E, N, countsP);
  int nb = (N + 255) / 256;
  int scanAddBlocks = (N + 1 + 255) / 256;
  k_scan_block<<<nb, 256, 0, stream>>>(countsA, N, rowptrA, blockSums);
  k_scan_sums<<<1, 256, 0, stream>>>(blockSums, nb);
  k_scan_add<<<scanAddBlocks, 256, 0, stream>>>(rowptrA, blockSums, N, nb);
  k_scan_block<<<nb, 256, 0, stream>>>(countsP, N, rowptrP, blockSums);
  k_scan_sums<<<1, 256, 0, stream>>>(blockSums, nb);
  k_scan_add<<<scanAddBlocks, 256, 0, stream>>>(rowptrP, blockSums, N, nb);
  k_fill<<<GS, 256, 0, stream>>>(ei, E, N, rowptrA, cursA, srcsA, nullptr, nullptr, scal);
  k_fill<<<GS, 256, 0, stream>>>(pei, E, N, rowptrP, cursP, srcsP, eaP, pea, scal);

  // layer 1: h = x @ W (both branches), att dots, aggregation (+bias +prelu)
  dim3 g1((N + 127) / 128, H1c / 64);
  gemm_f32t<128, 64, 32, 8, 4><<<g1, 256, 0, stream>>>(x, W1, h1a, N, H1c, D_IN);
  gemm_f32t<128, 64, 32, 8, 4><<<g1, 256, 0, stream>>>(x, pW1, h1p, N, H1c, D_IN);
  int gw = (N + 3) / 4;  // 4 waves per block, 1 node per wave
  k_node_dots<H1c><<<gw, 256, 0, stream>>>(h1a, att_src1, att_dst1, as_a, ad_a, N);
  k_node_dots<H1c><<<gw, 256, 0, stream>>>(h1p, patt_src1, patt_dst1, as_p, ad_p, N);
  k_gat_agg<H1c, false><<<gw, 256, 0, stream>>>(h1a, rowptrA, srcsA, nullptr, scal, 0,
                                                as_a, ad_a, b1, prelu_a, f1a, N);
  k_gat_agg<H1c, true><<<gw, 256, 0, stream>>>(h1p, rowptrP, srcsP, eaP, scal, 1,
                                               as_p, ad_p, pb1, pprelu_a, g1p, N);

  // layer 2
  dim3 g2((N + 63) / 64, H2c / 64);
  gemm_f32t<64, 64, 32, 4, 4><<<g2, 256, 0, stream>>>(f1a, W2, h2a, N, H2c, H1c);
  gemm_f32t<64, 64, 32, 4, 4><<<g2, 256, 0, stream>>>(g1p, pW2, h2p, N, H2c, H1c);
  k_node_dots<H2c><<<gw, 256, 0, stream>>>(h2a, att_src2, att_dst2, as_a, ad_a, N);
  k_node_dots<H2c><<<gw, 256, 0, stream>>>(h2p, patt_src2, patt_dst2, as_p, ad_p, N);
  k_gat_agg<H2c, false><<<gw, 256, 0, stream>>>(h2a, rowptrA, srcsA, nullptr, scal, 0,
                                                as_a, ad_a, b2, prelu_a, l_out, N);
  k_gat_agg<H2c, true><<<gw, 256, 0, stream>>>(h2p, rowptrP, srcsP, eaP, scal, 2,
                                               as_p, ad_p, pb2, pprelu_a, g_out, N);

  // fusion + classifier
  k_fuse<<<gw, 256, 0, stream>>>(l_out, g_out, attn_w, attn_b, clf_w, clf_b, out, N);
}

// Round 4
// 1171.255 us; speedup vs baseline: 1.6270x; 1.0794x over previous
//
#include <hip/hip_runtime.h>

// GraphDA: two 2-layer GAT branches + softmax fusion + classifier.
// Round-4 structure: merged dual-branch kernels, atomic-free CSR fill with
// nontemporal scatter stores, packed (src,ea) for the PPMI branch, direct-exp
// segment softmax (no max pass), dual-B layer-1 GEMM sharing the x tile.

static constexpr int D_IN = 512;
static constexpr int H1c  = 128;
static constexpr int H2c  = 64;
static constexpr int NCLS = 10;

#define DEV __device__ __forceinline__

DEV float waveReduceSum(float v) {
#pragma unroll
  for (int off = 32; off; off >>= 1) v += __shfl_xor(v, off);
  return v;
}

// ---------------- sum of E floats -> out[0] (for self-loop mean attr)
__global__ void k_sum(const float* __restrict__ x, int n, float* __restrict__ out) {
  float v = 0.f;
  for (int i = blockIdx.x * blockDim.x + threadIdx.x; i < n; i += gridDim.x * blockDim.x)
    v += x[i];
  v = waveReduceSum(v);
  if ((threadIdx.x & 63) == 0) atomicAdd(out, v);
}

// ---------------- c1 = dot(We1, ae1) [128], c2 = dot(We2, ae2) [64]
__global__ void k_edge_coef(const float* __restrict__ We1, const float* __restrict__ ae1,
                            const float* __restrict__ We2, const float* __restrict__ ae2,
                            float* __restrict__ scal) {
  int lane = threadIdx.x;
  float p1 = We1[lane] * ae1[lane] + We1[lane + 64] * ae1[lane + 64];
  float p2 = We2[lane] * ae2[lane];
  p1 = waveReduceSum(p1);
  p2 = waveReduceSum(p2);
  if (lane == 0) { scal[1] = p1; scal[2] = p2; }
}

// ---------------- histogram of dst for BOTH graphs; records per-edge slot seq
__global__ void k_count2(const int* __restrict__ eiA, const int* __restrict__ eiP,
                         int E, int n, int* __restrict__ countsA, int* __restrict__ countsP,
                         int* __restrict__ posA, int* __restrict__ posP) {
  int tot = E + n;
  int tot2 = 2 * tot;
  for (int i = blockIdx.x * blockDim.x + threadIdx.x; i < tot2; i += gridDim.x * blockDim.x) {
    bool isP = i >= tot;
    int e = isP ? i - tot : i;
    const int* ei = isP ? eiP : eiA;
    int* counts = isP ? countsP : countsA;
    int* pos = isP ? posP : posA;
    int d = (e < E) ? ei[(size_t)E + e] : (e - E);
    pos[e] = atomicAdd(&counts[d], 1);
  }
}

// ---------------- block-wise exclusive scan (3 kernels)
__global__ void k_scan_block(const int* __restrict__ counts, int n,
                             int* __restrict__ rowptr, int* __restrict__ blockSums) {
  __shared__ int buf[256];
  int tid = threadIdx.x;
  int i = blockIdx.x * 256 + tid;
  int v = (i < n) ? counts[i] : 0;
  buf[tid] = v;
  __syncthreads();
#pragma unroll
  for (int off = 1; off < 256; off <<= 1) {
    int t = (tid >= off) ? buf[tid - off] : 0;
    __syncthreads();
    buf[tid] += t;
    __syncthreads();
  }
  if (i < n) rowptr[i] = buf[tid] - v;  // local exclusive
  if (tid == 255) blockSums[blockIdx.x] = buf[255];
}

__global__ void k_scan_sums(int* __restrict__ bs, int nb) {
  __shared__ int buf[256];
  int tid = threadIdx.x;
  int v = (tid < nb) ? bs[tid] : 0;
  buf[tid] = v;
  __syncthreads();
#pragma unroll
  for (int off = 1; off < 256; off <<= 1) {
    int t = (tid >= off) ? buf[tid - off] : 0;
    __syncthreads();
    buf[tid] += t;
    __syncthreads();
  }
  if (tid < nb) bs[tid] = buf[tid] - v;  // exclusive
  if (tid == 255) bs[nb] = buf[255];     // total
}

__global__ void k_scan_add(int* __restrict__ rowptr, const int* __restrict__ bs, int n, int nb) {
  int i = blockIdx.x * blockDim.x + threadIdx.x;
  if (i < n) rowptr[i] += bs[i >> 8];
  else if (i == n) rowptr[n] = bs[nb];
}

// ---------------- atomic-free CSR fill for BOTH graphs (nontemporal scatter)
__global__ void k_fill2(const int* __restrict__ eiA, const int* __restrict__ eiP,
                        const float* __restrict__ pea, int E, int n,
                        const int* __restrict__ rowptrA, const int* __restrict__ rowptrP,
                        const int* __restrict__ posA, const int* __restrict__ posP,
                        int* __restrict__ srcsA, int2* __restrict__ packP,
                        const float* __restrict__ scal) {
  int tot = E + n;
  int tot2 = 2 * tot;
  float meanea = scal[0] / (float)E;
  for (int i = blockIdx.x * blockDim.x + threadIdx.x; i < tot2; i += gridDim.x * blockDim.x) {
    if (i < tot) {  // adjacency graph: src only
      int e = i;
      int s, d;
      if (e < E) { s = eiA[e]; d = eiA[(size_t)E + e]; }
      else { s = d = e - E; }
      int slot = rowptrA[d] + posA[e];
      __builtin_nontemporal_store(s, &srcsA[slot]);
    } else {  // ppmi graph: pack (src, edge_attr) into 8B
      int e = i - tot;
      int s, d;
      float ev;
      if (e < E) { s = eiP[e]; d = eiP[(size_t)E + e]; ev = pea[e]; }
      else { s = d = e - E; ev = meanea; }
      int slot = rowptrP[d] + posP[e];
      unsigned long long u =
          ((unsigned long long)__float_as_uint(ev) << 32) | (unsigned int)s;
      __builtin_nontemporal_store(u, (unsigned long long*)&packP[slot]);
    }
  }
}

// ---------------- dual-B tiled f32 GEMM: C1 = A@B1, C2 = A@B2 (shared A tile)
template <int BM, int BN, int BK, int TM, int TN>
__global__ __launch_bounds__(256) void gemm_f32t_dual(const float* __restrict__ A,
                                                      const float* __restrict__ B1,
                                                      const float* __restrict__ B2,
                                                      float* __restrict__ C1,
                                                      float* __restrict__ C2,
                                                      int M, int N, int K) {
  __shared__ float As[BK][BM + 4];  // transposed: As[k][m]
  __shared__ float B1s[BK][BN + 4];
  __shared__ float B2s[BK][BN + 4];
  constexpr int TX = BN / TN;
  const int tid = threadIdx.x;
  const int tx = tid % TX;
  const int ty = tid / TX;
  const int rowBase = blockIdx.x * BM;
  const int colBase = blockIdx.y * BN;
  float acc1[TM][TN] = {}, acc2[TM][TN] = {};
  constexpr int A4 = (BM * BK / 4) / 256;
  constexpr int B4 = (BN * BK / 4) / 256;
  for (int k0 = 0; k0 < K; k0 += BK) {
#pragma unroll
    for (int it = 0; it < A4; ++it) {
      int idx = it * 256 + tid;
      int row = idx / (BK / 4);
      int cv = (idx % (BK / 4)) * 4;
      int gr = rowBase + row;
      float4 v = make_float4(0.f, 0.f, 0.f, 0.f);
      if (gr < M) v = *(const float4*)(A + (size_t)gr * K + k0 + cv);
      As[cv + 0][row] = v.x;
      As[cv + 1][row] = v.y;
      As[cv + 2][row] = v.z;
      As[cv + 3][row] = v.w;
    }
#pragma unroll
    for (int it = 0; it < B4; ++it) {
      int idx = it * 256 + tid;
      int r = idx / (BN / 4);
      int c = (idx % (BN / 4)) * 4;
      *(float4*)&B1s[r][c] = *(const float4*)(B1 + (size_t)(k0 + r) * N + colBase + c);
      *(float4*)&B2s[r][c] = *(const float4*)(B2 + (size_t)(k0 + r) * N + colBase + c);
    }
    __syncthreads();
#pragma unroll
    for (int kk = 0; kk < BK; ++kk) {
      float a[TM], b1[TN], b2[TN];
#pragma unroll
      for (int i = 0; i < TM; i += 4) *(float4*)&a[i] = *(const float4*)&As[kk][ty * TM + i];
#pragma unroll
      for (int j = 0; j < TN; j += 4) {
        *(float4*)&b1[j] = *(const float4*)&B1s[kk][tx * TN + j];
        *(float4*)&b2[j] = *(const float4*)&B2s[kk][tx * TN + j];
      }
#pragma unroll
      for (int i = 0; i < TM; ++i)
#pragma unroll
        for (int j = 0; j < TN; ++j) {
          acc1[i][j] = fmaf(a[i], b1[j], acc1[i][j]);
          acc2[i][j] = fmaf(a[i], b2[j], acc2[i][j]);
        }
    }
    __syncthreads();
  }
#pragma unroll
  for (int i = 0; i < TM; ++i) {
    int gr = rowBase + ty * TM + i;
    if (gr < M) {
      float* c1p = C1 + (size_t)gr * N + colBase + tx * TN;
      float* c2p = C2 + (size_t)gr * N + colBase + tx * TN;
#pragma unroll
      for (int j = 0; j < TN; j += 4) {
        *(float4*)&c1p[j] = *(const float4*)&acc1[i][j];
        *(float4*)&c2p[j] = *(const float4*)&acc2[i][j];
      }
    }
  }
}

// ---------------- single tiled f32 GEMM (layer 2)
template <int BM, int BN, int BK, int TM, int TN>
__global__ __launch_bounds__(256) void gemm_f32t(const float* __restrict__ A,
                                                 const float* __restrict__ B,
                                                 float* __restrict__ C, int M, int N, int K) {
  __shared__ float As[BK][BM + 4];
  __shared__ float Bs[BK][BN + 4];
  constexpr int TX = BN / TN;
  const int tid = threadIdx.x;
  const int tx = tid % TX;
  const int ty = tid / TX;
  const int rowBase = blockIdx.x * BM;
  const int colBase = blockIdx.y * BN;
  float acc[TM][TN] = {};
  constexpr int A4 = (BM * BK / 4) / 256;
  constexpr int B4 = (BN * BK / 4) / 256;
  for (int k0 = 0; k0 < K; k0 += BK) {
#pragma unroll
    for (int it = 0; it < A4; ++it) {
      int idx = it * 256 + tid;
      int row = idx / (BK / 4);
      int cv = (idx % (BK / 4)) * 4;
      int gr = rowBase + row;
      float4 v = make_float4(0.f, 0.f, 0.f, 0.f);
      if (gr < M) v = *(const float4*)(A + (size_t)gr * K + k0 + cv);
      As[cv + 0][row] = v.x;
      As[cv + 1][row] = v.y;
      As[cv + 2][row] = v.z;
      As[cv + 3][row] = v.w;
    }
#pragma unroll
    for (int it = 0; it < B4; ++it) {
      int idx = it * 256 + tid;
      int r = idx / (BN / 4);
      int c = (idx % (BN / 4)) * 4;
      *(float4*)&Bs[r][c] = *(const float4*)(B + (size_t)(k0 + r) * N + colBase + c);
    }
    __syncthreads();
#pragma unroll
    for (int kk = 0; kk < BK; ++kk) {
      float a[TM], b[TN];
#pragma unroll
      for (int i = 0; i < TM; i += 4) *(float4*)&a[i] = *(const float4*)&As[kk][ty * TM + i];
#pragma unroll
      for (int j = 0; j < TN; j += 4) *(float4*)&b[j] = *(const float4*)&Bs[kk][tx * TN + j];
#pragma unroll
      for (int i = 0; i < TM; ++i)
#pragma unroll
        for (int j = 0; j < TN; ++j) acc[i][j] = fmaf(a[i], b[j], acc[i][j]);
    }
    __syncthreads();
  }
#pragma unroll
  for (int i = 0; i < TM; ++i) {
    int gr = rowBase + ty * TM + i;
    if (gr < M) {
      float* cp = C + (size_t)gr * N + colBase + tx * TN;
#pragma unroll
      for (int j = 0; j < TN; j += 4) *(float4*)&cp[j] = *(const float4*)&acc[i][j];
    }
  }
}

// ---------------- per-node att dots for BOTH branches: blockIdx.y = branch
template <int DIM>
__global__ void k_node_dots2(const float* __restrict__ hA, const float* __restrict__ hP,
                             const float* __restrict__ vaA, const float* __restrict__ vbA,
                             const float* __restrict__ vaP, const float* __restrict__ vbP,
                             float* __restrict__ asA, float* __restrict__ adA,
                             float* __restrict__ asP, float* __restrict__ adP, int n) {
  int wid = (blockIdx.x * blockDim.x + threadIdx.x) >> 6;
  int lane = threadIdx.x & 63;
  if (wid >= n) return;
  bool isP = blockIdx.y != 0;
  const float* h = isP ? hP : hA;
  const float* va = isP ? vaP : vaA;
  const float* vb = isP ? vbP : vbA;
  float* oa = isP ? asP : asA;
  float* ob = isP ? adP : adA;
  const float* hr = h + (size_t)wid * DIM;
  float pa = 0.f, pb = 0.f;
#pragma unroll
  for (int v = 0; v < DIM / 64; ++v) {
    float xv = hr[lane + 64 * v];
    pa += xv * va[lane + 64 * v];
    pb += xv * vb[lane + 64 * v];
  }
  pa = waveReduceSum(pa);
  pb = waveReduceSum(pb);
  if (lane == 0) { oa[wid] = pa; ob[wid] = pb; }
}

DEV float leaky02(float a) { return a > 0.f ? a : 0.2f * a; }
DEV float expw(float a) { return __expf(fminf(a, 80.f)); }  // direct exp, overflow guard

// ---------------- GAT aggregation, BOTH branches (blockIdx.y), direct-exp
// softmax, x4-unrolled gathers. A branch: int srcs; P branch: packed (src,ea).
template <int DIM>
__global__ void k_gat_agg2(const float* __restrict__ hA, const float* __restrict__ hP,
                           const int* __restrict__ rowptrA, const int* __restrict__ rowptrP,
                           const int* __restrict__ srcsA, const int2* __restrict__ packP,
                           const float* __restrict__ scal, int scal_idx,
                           const float* __restrict__ asA, const float* __restrict__ adA,
                           const float* __restrict__ asP, const float* __restrict__ adP,
                           const float* __restrict__ biasA, const float* __restrict__ biasP,
                           const float* __restrict__ paA, const float* __restrict__ paP,
                           float* __restrict__ outA, float* __restrict__ outP, int n) {
  int wid = (blockIdx.x * blockDim.x + threadIdx.x) >> 6;
  int lane = threadIdx.x & 63;
  if (wid >= n) return;
  bool isP = blockIdx.y != 0;
  const float* h = isP ? hP : hA;
  const int* rowptr = isP ? rowptrP : rowptrA;
  const float* as_ = isP ? asP : asA;
  const float* bias = isP ? biasP : biasA;
  const float* out_ = isP ? outP : outA;
  float adv = (isP ? adP : adA)[wid];
  float pa = (isP ? paP : paA)[0];
  float c = isP ? scal[scal_idx] : 0.f;
  int e0 = rowptr[wid], e1 = rowptr[wid + 1];
  float ssum = 0.f;
  if constexpr (DIM == 128) {
    float2 acc = make_float2(0.f, 0.f);
    int e = e0;
    for (; e + 4 <= e1; e += 4) {
      int s0, s1, s2, s3;
      float a0, a1, a2, a3;
      if (isP) {
        int2 p0 = packP[e], p1 = packP[e + 1], p2 = packP[e + 2], p3 = packP[e + 3];
        s0 = p0.x; s1 = p1.x; s2 = p2.x; s3 = p3.x;
        a0 = c * __int_as_float(p0.y); a1 = c * __int_as_float(p1.y);
        a2 = c * __int_as_float(p2.y); a3 = c * __int_as_float(p3.y);
      } else {
        s0 = srcsA[e]; s1 = srcsA[e + 1]; s2 = srcsA[e + 2]; s3 = srcsA[e + 3];
        a0 = a1 = a2 = a3 = 0.f;
      }
      a0 += as_[s0] + adv; a1 += as_[s1] + adv; a2 += as_[s2] + adv; a3 += as_[s3] + adv;
      float2 h0 = ((const float2*)(h + (size_t)s0 * 128))[lane];
      float2 h1 = ((const float2*)(h + (size_t)s1 * 128))[lane];
      float2 h2 = ((const float2*)(h + (size_t)s2 * 128))[lane];
      float2 h3 = ((const float2*)(h + (size_t)s3 * 128))[lane];
      float w0 = expw(leaky02(a0)), w1 = expw(leaky02(a1));
      float w2 = expw(leaky02(a2)), w3 = expw(leaky02(a3));
      ssum += (w0 + w1) + (w2 + w3);
      acc.x += w0 * h0.x + w1 * h1.x + w2 * h2.x + w3 * h3.x;
      acc.y += w0 * h0.y + w1 * h1.y + w2 * h2.y + w3 * h3.y;
    }
    for (; e < e1; ++e) {
      int s;
      float a;
      if (isP) {
        int2 p = packP[e];
        s = p.x;
        a = c * __int_as_float(p.y);
      } else {
        s = srcsA[e];
        a = 0.f;
      }
      a += as_[s] + adv;
      float w = expw(leaky02(a));
      ssum += w;
      float2 hv = ((const float2*)(h + (size_t)s * 128))[lane];
      acc.x += w * hv.x;
      acc.y += w * hv.y;
    }
    float inv = 1.f / (ssum + 1e-16f);
    float2 bv = ((const float2*)bias)[lane];
    float ox = acc.x * inv + bv.x;
    float oy = acc.y * inv + bv.y;
    ox = ox >= 0.f ? ox : pa * ox;
    oy = oy >= 0.f ? oy : pa * oy;
    ((float2*)((float*)out_ + (size_t)wid * 128))[lane] = make_float2(ox, oy);
  } else {
    float acc = 0.f;
    int e = e0;
    for (; e + 4 <= e1; e += 4) {
      int s0, s1, s2, s3;
      float a0, a1, a2, a3;
      if (isP) {
        int2 p0 = packP[e], p1 = packP[e + 1], p2 = packP[e + 2], p3 = packP[e + 3];
        s0 = p0.x; s1 = p1.x; s2 = p2.x; s3 = p3.x;
        a0 = c * __int_as_float(p0.y); a1 = c * __int_as_float(p1.y);
        a2 = c * __int_as_float(p2.y); a3 = c * __int_as_float(p3.y);
      } else {
        s0 = srcsA[e]; s1 = srcsA[e + 1]; s2 = srcsA[e + 2]; s3 = srcsA[e + 3];
        a0 = a1 = a2 = a3 = 0.f;
      }
      a0 += as_[s0] + adv; a1 += as_[s1] + adv; a2 += as_[s2] + adv; a3 += as_[s3] + adv;
      float h0 = h[(size_t)s0 * 64 + lane];
      float h1 = h[(size_t)s1 * 64 + lane];
      float h2 = h[(size_t)s2 * 64 + lane];
      float h3 = h[(size_t)s3 * 64 + lane];
      float w0 = expw(leaky02(a0)), w1 = expw(leaky02(a1));
      float w2 = expw(leaky02(a2)), w3 = expw(leaky02(a3));
      ssum += (w0 + w1) + (w2 + w3);
      acc += w0 * h0 + w1 * h1 + w2 * h2 + w3 * h3;
    }
    for (; e < e1; ++e) {
      int s;
      float a;
      if (isP) {
        int2 p = packP[e];
        s = p.x;
        a = c * __int_as_float(p.y);
      } else {
        s = srcsA[e];
        a = 0.f;
      }
      a += as_[s] + adv;
      float w = expw(leaky02(a));
      ssum += w;
      acc += w * h[(size_t)s * 64 + lane];
    }
    float inv = 1.f / (ssum + 1e-16f);
    float o = acc * inv + bias[lane];
    o = o >= 0.f ? o : pa * o;
    ((float*)out_)[(size_t)wid * 64 + lane] = o;
  }
}

// ---------------- fusion softmax + classifier: one wave per node
__global__ void k_fuse(const float* __restrict__ lout, const float* __restrict__ gout,
                       const float* __restrict__ attn_w, const float* __restrict__ attn_b,
                       const float* __restrict__ clf_w, const float* __restrict__ clf_b,
                       float* __restrict__ out, int n) {
  int wid = (blockIdx.x * blockDim.x + threadIdx.x) >> 6;
  int lane = threadIdx.x & 63;
  if (wid >= n) return;
  float l = lout[(size_t)wid * 64 + lane];
  float g = gout[(size_t)wid * 64 + lane];
  float aw = attn_w[lane];
  float s0 = waveReduceSum(l * aw) + attn_b[0];
  float s1 = waveReduceSum(g * aw) + attn_b[0];
  float mx = fmaxf(s0, s1);
  float e0 = __expf(s0 - mx), e1 = __expf(s1 - mx);
  float inv = 1.f / (e0 + e1);
  float w0 = e0 * inv, w1 = e1 * inv;
  float emb = w0 * l + w1 * g;
  out[(size_t)wid * 64 + lane] = emb;
  float p[NCLS];
#pragma unroll
  for (int cc = 0; cc < NCLS; ++cc) p[cc] = emb * clf_w[lane * NCLS + cc];
#pragma unroll
  for (int off = 32; off; off >>= 1)
#pragma unroll
    for (int cc = 0; cc < NCLS; ++cc) p[cc] += __shfl_xor(p[cc], off);
  if (lane < NCLS) {
    float val = 0.f;
#pragma unroll
    for (int cc = 0; cc < NCLS; ++cc)
      if (lane == cc) val = p[cc];
    out[(size_t)n * 64 + (size_t)wid * NCLS + lane] = val + clf_b[lane];
  }
}

extern "C" void kernel_launch(void* const* d_in, const int* in_sizes, int n_in,
                              void* d_out, int out_size, void* d_ws, size_t ws_size,
                              hipStream_t stream) {
  const float* x         = (const float*)d_in[0];
  const int*   ei        = (const int*)d_in[1];
  const int*   pei       = (const int*)d_in[2];
  const float* pea       = (const float*)d_in[3];
  const float* W1        = (const float*)d_in[4];
  const float* att_src1  = (const float*)d_in[5];
  const float* att_dst1  = (const float*)d_in[6];
  const float* b1        = (const float*)d_in[7];
  const float* W2        = (const float*)d_in[8];
  const float* att_src2  = (const float*)d_in[9];
  const float* att_dst2  = (const float*)d_in[10];
  const float* b2        = (const float*)d_in[11];
  const float* prelu_a   = (const float*)d_in[12];
  const float* pW1       = (const float*)d_in[13];
  const float* patt_src1 = (const float*)d_in[14];
  const float* patt_dst1 = (const float*)d_in[15];
  const float* pWe1      = (const float*)d_in[16];
  const float* patt_e1   = (const float*)d_in[17];
  const float* pb1       = (const float*)d_in[18];
  const float* pW2       = (const float*)d_in[19];
  const float* patt_src2 = (const float*)d_in[20];
  const float* patt_dst2 = (const float*)d_in[21];
  const float* pWe2      = (const float*)d_in[22];
  const float* patt_e2   = (const float*)d_in[23];
  const float* pb2       = (const float*)d_in[24];
  const float* pprelu_a  = (const float*)d_in[25];
  const float* attn_w    = (const float*)d_in[26];
  const float* attn_b    = (const float*)d_in[27];
  const float* clf_w     = (const float*)d_in[28];
  const float* clf_b     = (const float*)d_in[29];
  float* out = (float*)d_out;

  const int N = in_sizes[0] / D_IN;
  const int E = in_sizes[1] / 2;
  const int Etot = E + N;

  // ---- workspace layout (floats, then ints)
  float* wf = (float*)d_ws;
  size_t o = 0;
  float* h1a = wf + o; o += (size_t)N * H1c;
  float* h1p = wf + o; o += (size_t)N * H1c;
  float* f1a = wf + o; o += (size_t)N * H1c;
  float* g1p = wf + o; o += (size_t)N * H1c;
  float* as_a = wf + o; o += N;
  float* ad_a = wf + o; o += N;
  float* as_p = wf + o; o += N;
  float* ad_p = wf + o; o += N;
  float* scal = wf + o; o += 8;  // [0]=sum(pea), [1]=c1, [2]=c2
  // layer-2 tensors overlay the (then-dead) layer-1 h buffers:
  float* h2a   = h1a;
  float* l_out = h1a + (size_t)N * H2c;
  float* h2p   = h1p;
  float* g_out = h1p + (size_t)N * H2c;
  // pos arrays alias h1a region too (dead before gemm writes h1a):
  int* posA = (int*)f1a;        // Etot ints  (f1a written after fill)
  int* posP = posA + Etot;      // fits: Etot*2 ints = 13.2MB < 25.6MB

  int* wi = (int*)(wf + o);
  int* rowptrA = wi;
  int* rowptrP = rowptrA + (N + 1);
  int* countsA = rowptrP + (N + 1);
  int* countsP = countsA + N;
  int* blockSums = countsP + N;  // 512 ints
  int* srcsA = blockSums + 512;
  int2* packP = (int2*)(srcsA + Etot);
  size_t needBytes = (size_t)((char*)(packP + Etot) - (char*)d_ws);
  if (needBytes > ws_size) return;  // would corrupt; fail loudly (output stays zero)

  hipMemsetAsync(countsA, 0, sizeof(int) * (size_t)2 * N, stream);
  hipMemsetAsync(scal, 0, sizeof(float) * 8, stream);

  const int GS = 2048;
  // self-loop mean attr + edge coefficient scalars
  k_sum<<<1024, 256, 0, stream>>>(pea, E, scal);
  k_edge_coef<<<1, 64, 0, stream>>>(pWe1, patt_e1, pWe2, patt_e2, scal);

  // CSR build for both graphs (merged kernels)
  k_count2<<<GS, 256, 0, stream>>>(ei, pei, E, N, countsA, countsP, posA, posP);
  int nb = (N + 255) / 256;
  int scanAddBlocks = (N + 1 + 255) / 256;
  k_scan_block<<<nb, 256, 0, stream>>>(countsA, N, rowptrA, blockSums);
  k_scan_sums<<<1, 256, 0, stream>>>(blockSums, nb);
  k_scan_add<<<scanAddBlocks, 256, 0, stream>>>(rowptrA, blockSums, N, nb);
  k_scan_block<<<nb, 256, 0, stream>>>(countsP, N, rowptrP, blockSums);
  k_scan_sums<<<1, 256, 0, stream>>>(blockSums, nb);
  k_scan_add<<<scanAddBlocks, 256, 0, stream>>>(rowptrP, blockSums, N, nb);
  k_fill2<<<GS, 256, 0, stream>>>(ei, pei, pea, E, N, rowptrA, rowptrP, posA, posP,
                                  srcsA, packP, scal);

  // layer 1: h = x @ {W1,pW1} (shared-A dual GEMM), att dots, aggregation
  dim3 g1((N + 127) / 128, H1c / 64);
  gemm_f32t_dual<128, 64, 32, 8, 4><<<g1, 256, 0, stream>>>(x, W1, pW1, h1a, h1p, N, H1c, D_IN);
  int gw = (N + 3) / 4;  // 4 waves per block, 1 node per wave
  dim3 gd(gw, 2);
  k_node_dots2<H1c><<<gd, 256, 0, stream>>>(h1a, h1p, att_src1, att_dst1, patt_src1,
                                            patt_dst1, as_a, ad_a, as_p, ad_p, N);
  k_gat_agg2<H1c><<<gd, 256, 0, stream>>>(h1a, h1p, rowptrA, rowptrP, srcsA, packP, scal, 1,
                                          as_a, ad_a, as_p, ad_p, b1, pb1, prelu_a, pprelu_a,
                                          f1a, g1p, N);

  // layer 2
  dim3 g2((N + 63) / 64, H2c / 64);
  gemm_f32t<64, 64, 32, 4, 4><<<g2, 256, 0, stream>>>(f1a, W2, h2a, N, H2c, H1c);
  gemm_f32t<64, 64, 32, 4, 4><<<g2, 256, 0, stream>>>(g1p, pW2, h2p, N, H2c, H1c);
  k_node_dots2<H2c><<<gd, 256, 0, stream>>>(h2a, h2p, att_src2, att_dst2, patt_src2,
                                            patt_dst2, as_a, ad_a, as_p, ad_p, N);
  k_gat_agg2<H2c><<<gd, 256, 0, stream>>>(h2a, h2p, rowptrA, rowptrP, srcsA, packP, scal, 2,
                                          as_a, ad_a, as_p, ad_p, b2, pb2, prelu_a, pprelu_a,
                                          l_out, g_out, N);

  // fusion + classifier
  k_fuse<<<gw, 256, 0, stream>>>(l_out, g_out, attn_w, attn_b, clf_w, clf_b, out, N);
}

// Round 6
// 1003.678 us; speedup vs baseline: 1.8986x; 1.1670x over previous
//
#include <hip/hip_runtime.h>
#include <hip/hip_fp16.h>

// GraphDA: two 2-layer GAT branches + softmax fusion + classifier.
// Round-5: fp16 h for the gather path, chunked lane-parallel alpha with
// shuffle-broadcast accumulation, 32-bit gather offsets, merged L2 GEMMs.

static constexpr int D_IN = 512;
static constexpr int H1c  = 128;
static constexpr int H2c  = 64;
static constexpr int NCLS = 10;

#define DEV __device__ __forceinline__

DEV float waveReduceSum(float v) {
#pragma unroll
  for (int off = 32; off; off >>= 1) v += __shfl_xor(v, off);
  return v;
}

// ---------------- sum of E floats -> out[0] (for self-loop mean attr)
__global__ void k_sum(const float* __restrict__ x, int n, float* __restrict__ out) {
  float v = 0.f;
  for (int i = blockIdx.x * blockDim.x + threadIdx.x; i < n; i += gridDim.x * blockDim.x)
    v += x[i];
  v = waveReduceSum(v);
  if ((threadIdx.x & 63) == 0) atomicAdd(out, v);
}

// ---------------- c1 = dot(We1, ae1) [128], c2 = dot(We2, ae2) [64]
__global__ void k_edge_coef(const float* __restrict__ We1, const float* __restrict__ ae1,
                            const float* __restrict__ We2, const float* __restrict__ ae2,
                            float* __restrict__ scal) {
  int lane = threadIdx.x;
  float p1 = We1[lane] * ae1[lane] + We1[lane + 64] * ae1[lane + 64];
  float p2 = We2[lane] * ae2[lane];
  p1 = waveReduceSum(p1);
  p2 = waveReduceSum(p2);
  if (lane == 0) { scal[1] = p1; scal[2] = p2; }
}

// ---------------- histogram of dst for BOTH graphs; records per-edge slot seq
__global__ void k_count2(const int* __restrict__ eiA, const int* __restrict__ eiP,
                         int E, int n, int* __restrict__ countsA, int* __restrict__ countsP,
                         int* __restrict__ posA, int* __restrict__ posP) {
  int tot = E + n;
  int tot2 = 2 * tot;
  for (int i = blockIdx.x * blockDim.x + threadIdx.x; i < tot2; i += gridDim.x * blockDim.x) {
    bool isP = i >= tot;
    int e = isP ? i - tot : i;
    const int* ei = isP ? eiP : eiA;
    int* counts = isP ? countsP : countsA;
    int* pos = isP ? posP : posA;
    int d = (e < E) ? ei[(size_t)E + e] : (e - E);
    pos[e] = atomicAdd(&counts[d], 1);
  }
}

// ---------------- block-wise exclusive scan (3 kernels)
__global__ void k_scan_block(const int* __restrict__ counts, int n,
                             int* __restrict__ rowptr, int* __restrict__ blockSums) {
  __shared__ int buf[256];
  int tid = threadIdx.x;
  int i = blockIdx.x * 256 + tid;
  int v = (i < n) ? counts[i] : 0;
  buf[tid] = v;
  __syncthreads();
#pragma unroll
  for (int off = 1; off < 256; off <<= 1) {
    int t = (tid >= off) ? buf[tid - off] : 0;
    __syncthreads();
    buf[tid] += t;
    __syncthreads();
  }
  if (i < n) rowptr[i] = buf[tid] - v;  // local exclusive
  if (tid == 255) blockSums[blockIdx.x] = buf[255];
}

__global__ void k_scan_sums(int* __restrict__ bs, int nb) {
  __shared__ int buf[256];
  int tid = threadIdx.x;
  int v = (tid < nb) ? bs[tid] : 0;
  buf[tid] = v;
  __syncthreads();
#pragma unroll
  for (int off = 1; off < 256; off <<= 1) {
    int t = (tid >= off) ? buf[tid - off] : 0;
    __syncthreads();
    buf[tid] += t;
    __syncthreads();
  }
  if (tid < nb) bs[tid] = buf[tid] - v;  // exclusive
  if (tid == 255) bs[nb] = buf[255];     // total
}

__global__ void k_scan_add(int* __restrict__ rowptr, const int* __restrict__ bs, int n, int nb) {
  int i = blockIdx.x * blockDim.x + threadIdx.x;
  if (i < n) rowptr[i] += bs[i >> 8];
  else if (i == n) rowptr[n] = bs[nb];
}

// ---------------- atomic-free CSR fill for BOTH graphs (nontemporal scatter)
__global__ void k_fill2(const int* __restrict__ eiA, const int* __restrict__ eiP,
                        const float* __restrict__ pea, int E, int n,
                        const int* __restrict__ rowptrA, const int* __restrict__ rowptrP,
                        const int* __restrict__ posA, const int* __restrict__ posP,
                        int* __restrict__ srcsA, int2* __restrict__ packP,
                        const float* __restrict__ scal) {
  int tot = E + n;
  int tot2 = 2 * tot;
  float meanea = scal[0] / (float)E;
  for (int i = blockIdx.x * blockDim.x + threadIdx.x; i < tot2; i += gridDim.x * blockDim.x) {
    if (i < tot) {
      int e = i;
      int s, d;
      if (e < E) { s = eiA[e]; d = eiA[(size_t)E + e]; }
      else { s = d = e - E; }
      int slot = rowptrA[d] + posA[e];
      __builtin_nontemporal_store(s, &srcsA[slot]);
    } else {
      int e = i - tot;
      int s, d;
      float ev;
      if (e < E) { s = eiP[e]; d = eiP[(size_t)E + e]; ev = pea[e]; }
      else { s = d = e - E; ev = meanea; }
      int slot = rowptrP[d] + posP[e];
      unsigned long long u =
          ((unsigned long long)__float_as_uint(ev) << 32) | (unsigned int)s;
      __builtin_nontemporal_store(u, (unsigned long long*)&packP[slot]);
    }
  }
}

// ---------------- dual-B tiled f32 GEMM, fp16 output: C1=A@B1, C2=A@B2
template <int BM, int BN, int BK, int TM, int TN>
__global__ __launch_bounds__(256) void gemm_dual_h(const float* __restrict__ A,
                                                   const float* __restrict__ B1,
                                                   const float* __restrict__ B2,
                                                   __half* __restrict__ C1,
                                                   __half* __restrict__ C2,
                                                   int M, int N, int K) {
  __shared__ float As[BK][BM + 4];  // transposed: As[k][m]
  __shared__ float B1s[BK][BN + 4];
  __shared__ float B2s[BK][BN + 4];
  constexpr int TX = BN / TN;
  const int tid = threadIdx.x;
  const int tx = tid % TX;
  const int ty = tid / TX;
  const int rowBase = blockIdx.x * BM;
  const int colBase = blockIdx.y * BN;
  float acc1[TM][TN] = {}, acc2[TM][TN] = {};
  constexpr int A4 = (BM * BK / 4) / 256;
  constexpr int B4 = (BN * BK / 4) / 256;
  for (int k0 = 0; k0 < K; k0 += BK) {
#pragma unroll
    for (int it = 0; it < A4; ++it) {
      int idx = it * 256 + tid;
      int row = idx / (BK / 4);
      int cv = (idx % (BK / 4)) * 4;
      int gr = rowBase + row;
      float4 v = make_float4(0.f, 0.f, 0.f, 0.f);
      if (gr < M) v = *(const float4*)(A + (size_t)gr * K + k0 + cv);
      As[cv + 0][row] = v.x;
      As[cv + 1][row] = v.y;
      As[cv + 2][row] = v.z;
      As[cv + 3][row] = v.w;
    }
#pragma unroll
    for (int it = 0; it < B4; ++it) {
      int idx = it * 256 + tid;
      int r = idx / (BN / 4);
      int c = (idx % (BN / 4)) * 4;
      *(float4*)&B1s[r][c] = *(const float4*)(B1 + (size_t)(k0 + r) * N + colBase + c);
      *(float4*)&B2s[r][c] = *(const float4*)(B2 + (size_t)(k0 + r) * N + colBase + c);
    }
    __syncthreads();
#pragma unroll
    for (int kk = 0; kk < BK; ++kk) {
      float a[TM], b1[TN], b2[TN];
#pragma unroll
      for (int i = 0; i < TM; i += 4) *(float4*)&a[i] = *(const float4*)&As[kk][ty * TM + i];
#pragma unroll
      for (int j = 0; j < TN; j += 4) {
        *(float4*)&b1[j] = *(const float4*)&B1s[kk][tx * TN + j];
        *(float4*)&b2[j] = *(const float4*)&B2s[kk][tx * TN + j];
      }
#pragma unroll
      for (int i = 0; i < TM; ++i)
#pragma unroll
        for (int j = 0; j < TN; ++j) {
          acc1[i][j] = fmaf(a[i], b1[j], acc1[i][j]);
          acc2[i][j] = fmaf(a[i], b2[j], acc2[i][j]);
        }
    }
    __syncthreads();
  }
#pragma unroll
  for (int i = 0; i < TM; ++i) {
    int gr = rowBase + ty * TM + i;
    if (gr < M) {
      __half* c1p = C1 + (size_t)gr * N + colBase + tx * TN;
      __half* c2p = C2 + (size_t)gr * N + colBase + tx * TN;
#pragma unroll
      for (int j = 0; j < TN; j += 2) {
        *(__half2*)&c1p[j] = __floats2half2_rn(acc1[i][j], acc1[i][j + 1]);
        *(__half2*)&c2p[j] = __floats2half2_rn(acc2[i][j], acc2[i][j + 1]);
      }
    }
  }
}

// ---------------- layer-2 pair GEMM (blockIdx.z selects branch), fp16 out
template <int BM, int BN, int BK, int TM, int TN>
__global__ __launch_bounds__(256) void gemm_pair_h(const float* __restrict__ A0,
                                                   const float* __restrict__ A1,
                                                   const float* __restrict__ B0,
                                                   const float* __restrict__ B1,
                                                   __half* __restrict__ C0,
                                                   __half* __restrict__ C1,
                                                   int M, int N, int K) {
  const float* A = blockIdx.z ? A1 : A0;
  const float* B = blockIdx.z ? B1 : B0;
  __half* C = blockIdx.z ? C1 : C0;
  __shared__ float As[BK][BM + 4];
  __shared__ float Bs[BK][BN + 4];
  constexpr int TX = BN / TN;
  const int tid = threadIdx.x;
  const int tx = tid % TX;
  const int ty = tid / TX;
  const int rowBase = blockIdx.x * BM;
  const int colBase = blockIdx.y * BN;
  float acc[TM][TN] = {};
  constexpr int A4 = (BM * BK / 4) / 256;
  constexpr int B4 = (BN * BK / 4) / 256;
  for (int k0 = 0; k0 < K; k0 += BK) {
#pragma unroll
    for (int it = 0; it < A4; ++it) {
      int idx = it * 256 + tid;
      int row = idx / (BK / 4);
      int cv = (idx % (BK / 4)) * 4;
      int gr = rowBase + row;
      float4 v = make_float4(0.f, 0.f, 0.f, 0.f);
      if (gr < M) v = *(const float4*)(A + (size_t)gr * K + k0 + cv);
      As[cv + 0][row] = v.x;
      As[cv + 1][row] = v.y;
      As[cv + 2][row] = v.z;
      As[cv + 3][row] = v.w;
    }
#pragma unroll
    for (int it = 0; it < B4; ++it) {
      int idx = it * 256 + tid;
      int r = idx / (BN / 4);
      int c = (idx % (BN / 4)) * 4;
      *(float4*)&Bs[r][c] = *(const float4*)(B + (size_t)(k0 + r) * N + colBase + c);
    }
    __syncthreads();
#pragma unroll
    for (int kk = 0; kk < BK; ++kk) {
      float a[TM], b[TN];
#pragma unroll
      for (int i = 0; i < TM; i += 4) *(float4*)&a[i] = *(const float4*)&As[kk][ty * TM + i];
#pragma unroll
      for (int j = 0; j < TN; j += 4) *(float4*)&b[j] = *(const float4*)&Bs[kk][tx * TN + j];
#pragma unroll
      for (int i = 0; i < TM; ++i)
#pragma unroll
        for (int j = 0; j < TN; ++j) acc[i][j] = fmaf(a[i], b[j], acc[i][j]);
    }
    __syncthreads();
  }
#pragma unroll
  for (int i = 0; i < TM; ++i) {
    int gr = rowBase + ty * TM + i;
    if (gr < M) {
      __half* cp = C + (size_t)gr * N + colBase + tx * TN;
#pragma unroll
      for (int j = 0; j < TN; j += 2)
        *(__half2*)&cp[j] = __floats2half2_rn(acc[i][j], acc[i][j + 1]);
    }
  }
}

// ---------------- per-node att dots for BOTH branches (fp16 h)
template <int DIM>
__global__ void k_node_dots2(const __half* __restrict__ hA, const __half* __restrict__ hP,
                             const float* __restrict__ vaA, const float* __restrict__ vbA,
                             const float* __restrict__ vaP, const float* __restrict__ vbP,
                             float* __restrict__ asA, float* __restrict__ adA,
                             float* __restrict__ asP, float* __restrict__ adP, int n) {
  int wid = (blockIdx.x * blockDim.x + threadIdx.x) >> 6;
  int lane = threadIdx.x & 63;
  if (wid >= n) return;
  bool isP = blockIdx.y != 0;
  const __half* h = isP ? hP : hA;
  const float* va = isP ? vaP : vaA;
  const float* vb = isP ? vbP : vbA;
  float* oa = isP ? asP : asA;
  float* ob = isP ? adP : adA;
  const __half* hr = h + (size_t)wid * DIM;
  float pa = 0.f, pb = 0.f;
#pragma unroll
  for (int v = 0; v < DIM / 64; ++v) {
    float xv = __half2float(hr[lane + 64 * v]);
    pa += xv * va[lane + 64 * v];
    pb += xv * vb[lane + 64 * v];
  }
  pa = waveReduceSum(pa);
  pb = waveReduceSum(pb);
  if (lane == 0) { oa[wid] = pa; ob[wid] = pb; }
}

DEV float leaky02(float a) { return a > 0.f ? a : 0.2f * a; }
DEV float expw(float a) { return __expf(fminf(a, 80.f)); }

// ---------------- GAT aggregation, BOTH branches, chunked lane-parallel
// alpha + shuffle-broadcast fp16 gather. One wave per dst node.
template <int DIM>
__global__ void k_gat_agg2(const __half* __restrict__ hA, const __half* __restrict__ hP,
                           const int* __restrict__ rowptrA, const int* __restrict__ rowptrP,
                           const int* __restrict__ srcsA, const int2* __restrict__ packP,
                           const float* __restrict__ scal, int scal_idx,
                           const float* __restrict__ asA, const float* __restrict__ adA,
                           const float* __restrict__ asP, const float* __restrict__ adP,
                           const float* __restrict__ biasA, const float* __restrict__ biasP,
                           const float* __restrict__ paA, const float* __restrict__ paP,
                           float* __restrict__ outA, float* __restrict__ outP, int n) {
  int wid = (blockIdx.x * blockDim.x + threadIdx.x) >> 6;
  int lane = threadIdx.x & 63;
  if (wid >= n) return;
  bool isP = blockIdx.y != 0;
  const char* hb = (const char*)(isP ? hP : hA);
  const int* rowptr = isP ? rowptrP : rowptrA;
  const float* as_ = isP ? asP : asA;
  const float* bias = isP ? biasP : biasA;
  float* outp = isP ? outP : outA;
  float adv = (isP ? adP : adA)[wid];
  float pa = (isP ? paP : paA)[0];
  float c = isP ? scal[scal_idx] : 0.f;
  int e0 = rowptr[wid], e1 = rowptr[wid + 1];
  float ssum = 0.f;
  float accx = 0.f, accy = 0.f;
  const unsigned lb = (DIM == 128) ? ((unsigned)lane << 2) : ((unsigned)lane << 1);
  for (int base = e0; base < e1; base += 64) {
    // phase 1: one edge per lane — coalesced loads, lane-parallel exp
    int ee = base + lane;
    float w = 0.f;
    int s = 0;
    if (ee < e1) {
      float a;
      if (isP) {
        int2 p = packP[ee];
        s = p.x;
        a = c * __int_as_float(p.y);
      } else {
        s = srcsA[ee];
        a = 0.f;
      }
      a += as_[s] + adv;
      w = expw(leaky02(a));
    }
    ssum += w;
    // phase 2: broadcast (w, s) and gather fp16 h rows (dim-parallel)
    int cnt = min(64, e1 - base);
    int j = 0;
    for (; j + 4 <= cnt; j += 4) {
      float w0 = __shfl(w, j), w1 = __shfl(w, j + 1);
      float w2 = __shfl(w, j + 2), w3 = __shfl(w, j + 3);
      int s0 = __shfl(s, j), s1 = __shfl(s, j + 1);
      int s2 = __shfl(s, j + 2), s3 = __shfl(s, j + 3);
      if constexpr (DIM == 128) {
        __half2 v0 = *(const __half2*)(hb + (((unsigned)s0 << 8) + lb));
        __half2 v1 = *(const __half2*)(hb + (((unsigned)s1 << 8) + lb));
        __half2 v2 = *(const __half2*)(hb + (((unsigned)s2 << 8) + lb));
        __half2 v3 = *(const __half2*)(hb + (((unsigned)s3 << 8) + lb));
        float2 f0 = __half22float2(v0), f1 = __half22float2(v1);
        float2 f2 = __half22float2(v2), f3 = __half22float2(v3);
        accx += w0 * f0.x + w1 * f1.x + w2 * f2.x + w3 * f3.x;
        accy += w0 * f0.y + w1 * f1.y + w2 * f2.y + w3 * f3.y;
      } else {
        float f0 = __half2float(*(const __half*)(hb + (((unsigned)s0 << 7) + lb)));
        float f1 = __half2float(*(const __half*)(hb + (((unsigned)s1 << 7) + lb)));
        float f2 = __half2float(*(const __half*)(hb + (((unsigned)s2 << 7) + lb)));
        float f3 = __half2float(*(const __half*)(hb + (((unsigned)s3 << 7) + lb)));
        accx += w0 * f0 + w1 * f1 + w2 * f2 + w3 * f3;
      }
    }
    for (; j < cnt; ++j) {
      float wj = __shfl(w, j);
      int sj = __shfl(s, j);
      if constexpr (DIM == 128) {
        float2 f = __half22float2(*(const __half2*)(hb + (((unsigned)sj << 8) + lb)));
        accx += wj * f.x;
        accy += wj * f.y;
      } else {
        accx += wj * __half2float(*(const __half*)(hb + (((unsigned)sj << 7) + lb)));
      }
    }
  }
  ssum = waveReduceSum(ssum);
  float inv = 1.f / (ssum + 1e-16f);
  if constexpr (DIM == 128) {
    float2 bv = ((const float2*)bias)[lane];
    float ox = accx * inv + bv.x;
    float oy = accy * inv + bv.y;
    ox = ox >= 0.f ? ox : pa * ox;
    oy = oy >= 0.f ? oy : pa * oy;
    ((float2*)(outp + (size_t)wid * 128))[lane] = make_float2(ox, oy);
  } else {
    float o = accx * inv + bias[lane];
    o = o >= 0.f ? o : pa * o;
    outp[(size_t)wid * 64 + lane] = o;
  }
}

// ---------------- fusion softmax + classifier: one wave per node
__global__ void k_fuse(const float* __restrict__ lout, const float* __restrict__ gout,
                       const float* __restrict__ attn_w, const float* __restrict__ attn_b,
                       const float* __restrict__ clf_w, const float* __restrict__ clf_b,
                       float* __restrict__ out, int n) {
  int wid = (blockIdx.x * blockDim.x + threadIdx.x) >> 6;
  int lane = threadIdx.x & 63;
  if (wid >= n) return;
  float l = lout[(size_t)wid * 64 + lane];
  float g = gout[(size_t)wid * 64 + lane];
  float aw = attn_w[lane];
  float s0 = waveReduceSum(l * aw) + attn_b[0];
  float s1 = waveReduceSum(g * aw) + attn_b[0];
  float mx = fmaxf(s0, s1);
  float e0 = __expf(s0 - mx), e1 = __expf(s1 - mx);
  float inv = 1.f / (e0 + e1);
  float w0 = e0 * inv, w1 = e1 * inv;
  float emb = w0 * l + w1 * g;
  out[(size_t)wid * 64 + lane] = emb;
  float p[NCLS];
#pragma unroll
  for (int cc = 0; cc < NCLS; ++cc) p[cc] = emb * clf_w[lane * NCLS + cc];
#pragma unroll
  for (int off = 32; off; off >>= 1)
#pragma unroll
    for (int cc = 0; cc < NCLS; ++cc) p[cc] += __shfl_xor(p[cc], off);
  if (lane < NCLS) {
    float val = 0.f;
#pragma unroll
    for (int cc = 0; cc < NCLS; ++cc)
      if (lane == cc) val = p[cc];
    out[(size_t)n * 64 + (size_t)wid * NCLS + lane] = val + clf_b[lane];
  }
}

extern "C" void kernel_launch(void* const* d_in, const int* in_sizes, int n_in,
                              void* d_out, int out_size, void* d_ws, size_t ws_size,
                              hipStream_t stream) {
  const float* x         = (const float*)d_in[0];
  const int*   ei        = (const int*)d_in[1];
  const int*   pei       = (const int*)d_in[2];
  const float* pea       = (const float*)d_in[3];
  const float* W1        = (const float*)d_in[4];
  const float* att_src1  = (const float*)d_in[5];
  const float* att_dst1  = (const float*)d_in[6];
  const float* b1        = (const float*)d_in[7];
  const float* W2        = (const float*)d_in[8];
  const float* att_src2  = (const float*)d_in[9];
  const float* att_dst2  = (const float*)d_in[10];
  const float* b2        = (const float*)d_in[11];
  const float* prelu_a   = (const float*)d_in[12];
  const float* pW1       = (const float*)d_in[13];
  const float* patt_src1 = (const float*)d_in[14];
  const float* patt_dst1 = (const float*)d_in[15];
  const float* pWe1      = (const float*)d_in[16];
  const float* patt_e1   = (const float*)d_in[17];
  const float* pb1       = (const float*)d_in[18];
  const float* pW2       = (const float*)d_in[19];
  const float* patt_src2 = (const float*)d_in[20];
  const float* patt_dst2 = (const float*)d_in[21];
  const float* pWe2      = (const float*)d_in[22];
  const float* patt_e2   = (const float*)d_in[23];
  const float* pb2       = (const float*)d_in[24];
  const float* pprelu_a  = (const float*)d_in[25];
  const float* attn_w    = (const float*)d_in[26];
  const float* attn_b    = (const float*)d_in[27];
  const float* clf_w     = (const float*)d_in[28];
  const float* clf_b     = (const float*)d_in[29];
  float* out = (float*)d_out;

  const int N = in_sizes[0] / D_IN;
  const int E = in_sizes[1] / 2;
  const int Etot = E + N;

  // ---- workspace: byte bump allocator, 256B-aligned blocks
  char* wsp = (char*)d_ws;
  size_t used = 0;
  auto alloc = [&](size_t bytes) {
    char* p = wsp + used;
    used += (bytes + 255) & ~(size_t)255;
    return p;
  };
  __half* h1a_h = (__half*)alloc((size_t)N * H1c * 2);
  __half* h1p_h = (__half*)alloc((size_t)N * H1c * 2);
  float*  f1a   = (float*)alloc((size_t)N * H1c * 4);
  float*  g1p   = (float*)alloc((size_t)N * H1c * 4);
  __half* h2a_h = (__half*)alloc((size_t)N * H2c * 2);
  __half* h2p_h = (__half*)alloc((size_t)N * H2c * 2);
  float*  as_a  = (float*)alloc((size_t)N * 4);
  float*  ad_a  = (float*)alloc((size_t)N * 4);
  float*  as_p  = (float*)alloc((size_t)N * 4);
  float*  ad_p  = (float*)alloc((size_t)N * 4);
  float*  scal  = (float*)alloc(64);
  int*    rowptrA = (int*)alloc((size_t)(N + 1) * 4);
  int*    rowptrP = (int*)alloc((size_t)(N + 1) * 4);
  int*    countsA = (int*)alloc((size_t)N * 4);
  int*    countsP = (int*)alloc((size_t)N * 4);
  int*    blockSums = (int*)alloc(513 * 4);
  int*    srcsA = (int*)alloc((size_t)Etot * 4);
  int2*   packP = (int2*)alloc((size_t)Etot * 8);
  // overlays: pos arrays live in f1a/g1p (written only after fill);
  // l_out/g_out live in h1 half-buffers (dead after layer-1 agg/dots).
  int* posA = (int*)f1a;
  int* posP = posA + Etot;
  float* l_out = (float*)h1a_h;  // N*H2 floats == N*H1c halves bytes
  float* g_out = (float*)h1p_h;
  if (used > ws_size) return;  // would corrupt; fail loudly (output stays zero)

  hipMemsetAsync(countsA, 0, sizeof(int) * (size_t)N, stream);
  hipMemsetAsync(countsP, 0, sizeof(int) * (size_t)N, stream);
  hipMemsetAsync(scal, 0, 64, stream);

  const int GS = 2048;
  k_sum<<<1024, 256, 0, stream>>>(pea, E, scal);
  k_edge_coef<<<1, 64, 0, stream>>>(pWe1, patt_e1, pWe2, patt_e2, scal);

  // CSR build for both graphs
  k_count2<<<GS, 256, 0, stream>>>(ei, pei, E, N, countsA, countsP, posA, posP);
  int nb = (N + 255) / 256;
  int scanAddBlocks = (N + 1 + 255) / 256;
  k_scan_block<<<nb, 256, 0, stream>>>(countsA, N, rowptrA, blockSums);
  k_scan_sums<<<1, 256, 0, stream>>>(blockSums, nb);
  k_scan_add<<<scanAddBlocks, 256, 0, stream>>>(rowptrA, blockSums, N, nb);
  k_scan_block<<<nb, 256, 0, stream>>>(countsP, N, rowptrP, blockSums);
  k_scan_sums<<<1, 256, 0, stream>>>(blockSums, nb);
  k_scan_add<<<scanAddBlocks, 256, 0, stream>>>(rowptrP, blockSums, N, nb);
  k_fill2<<<GS, 256, 0, stream>>>(ei, pei, pea, E, N, rowptrA, rowptrP, posA, posP,
                                  srcsA, packP, scal);

  // layer 1
  dim3 g1((N + 127) / 128, H1c / 64);
  gemm_dual_h<128, 64, 32, 8, 4><<<g1, 256, 0, stream>>>(x, W1, pW1, h1a_h, h1p_h,
                                                         N, H1c, D_IN);
  int gw = (N + 3) / 4;
  dim3 gd(gw, 2);
  k_node_dots2<H1c><<<gd, 256, 0, stream>>>(h1a_h, h1p_h, att_src1, att_dst1, patt_src1,
                                            patt_dst1, as_a, ad_a, as_p, ad_p, N);
  k_gat_agg2<H1c><<<gd, 256, 0, stream>>>(h1a_h, h1p_h, rowptrA, rowptrP, srcsA, packP,
                                          scal, 1, as_a, ad_a, as_p, ad_p, b1, pb1,
                                          prelu_a, pprelu_a, f1a, g1p, N);

  // layer 2 (both branches in one dispatch via blockIdx.z)
  dim3 g2((N + 63) / 64, H2c / 64, 2);
  gemm_pair_h<64, 64, 32, 4, 4><<<g2, 256, 0, stream>>>(f1a, g1p, W2, pW2, h2a_h, h2p_h,
                                                        N, H2c, H1c);
  k_node_dots2<H2c><<<gd, 256, 0, stream>>>(h2a_h, h2p_h, att_src2, att_dst2, patt_src2,
                                            patt_dst2, as_a, ad_a, as_p, ad_p, N);
  k_gat_agg2<H2c><<<gd, 256, 0, stream>>>(h2a_h, h2p_h, rowptrA, rowptrP, srcsA, packP,
                                          scal, 2, as_a, ad_a, as_p, ad_p, b2, pb2,
                                          prelu_a, pprelu_a, l_out, g_out, N);

  // fusion + classifier
  k_fuse<<<gw, 256, 0, stream>>>(l_out, g_out, attn_w, attn_b, clf_w, clf_b, out, N);
}

// Round 11
// 953.003 us; speedup vs baseline: 1.9996x; 1.0532x over previous
//
#include <hip/hip_runtime.h>
#include <hip/hip_fp16.h>

// GraphDA: two 2-layer GAT branches + softmax fusion + classifier.
// Round-7: layer-1 GEMM moved to fp16-input MFMA (f32 accum), LDS-free
// one-wave-per-16-row-strip structure; W pre-transposed to fp16 [n][k].
// Rest unchanged from round 6 (fp16 gather path, shuffle-broadcast agg).

static constexpr int D_IN = 512;
static constexpr int H1c  = 128;
static constexpr int H2c  = 64;
static constexpr int NCLS = 10;

typedef _Float16 f16x8v __attribute__((ext_vector_type(8)));
typedef float f32x4v __attribute__((ext_vector_type(4)));

#define DEV __device__ __forceinline__

DEV float waveReduceSum(float v) {
#pragma unroll
  for (int off = 32; off; off >>= 1) v += __shfl_xor(v, off);
  return v;
}

// ---------------- sum of E floats -> out[0] (for self-loop mean attr)
__global__ void k_sum(const float* __restrict__ x, int n, float* __restrict__ out) {
  float v = 0.f;
  for (int i = blockIdx.x * blockDim.x + threadIdx.x; i < n; i += gridDim.x * blockDim.x)
    v += x[i];
  v = waveReduceSum(v);
  if ((threadIdx.x & 63) == 0) atomicAdd(out, v);
}

// ---------------- c1 = dot(We1, ae1) [128], c2 = dot(We2, ae2) [64]
__global__ void k_edge_coef(const float* __restrict__ We1, const float* __restrict__ ae1,
                            const float* __restrict__ We2, const float* __restrict__ ae2,
                            float* __restrict__ scal) {
  int lane = threadIdx.x;
  float p1 = We1[lane] * ae1[lane] + We1[lane + 64] * ae1[lane + 64];
  float p2 = We2[lane] * ae2[lane];
  p1 = waveReduceSum(p1);
  p2 = waveReduceSum(p2);
  if (lane == 0) { scal[1] = p1; scal[2] = p2; }
}

// ---------------- histogram of dst for BOTH graphs; records per-edge slot seq
__global__ void k_count2(const int* __restrict__ eiA, const int* __restrict__ eiP,
                         int E, int n, int* __restrict__ countsA, int* __restrict__ countsP,
                         int* __restrict__ posA, int* __restrict__ posP) {
  int tot = E + n;
  int tot2 = 2 * tot;
  for (int i = blockIdx.x * blockDim.x + threadIdx.x; i < tot2; i += gridDim.x * blockDim.x) {
    bool isP = i >= tot;
    int e = isP ? i - tot : i;
    const int* ei = isP ? eiP : eiA;
    int* counts = isP ? countsP : countsA;
    int* pos = isP ? posP : posA;
    int d = (e < E) ? ei[(size_t)E + e] : (e - E);
    pos[e] = atomicAdd(&counts[d], 1);
  }
}

// ---------------- block-wise exclusive scan (3 kernels)
__global__ void k_scan_block(const int* __restrict__ counts, int n,
                             int* __restrict__ rowptr, int* __restrict__ blockSums) {
  __shared__ int buf[256];
  int tid = threadIdx.x;
  int i = blockIdx.x * 256 + tid;
  int v = (i < n) ? counts[i] : 0;
  buf[tid] = v;
  __syncthreads();
#pragma unroll
  for (int off = 1; off < 256; off <<= 1) {
    int t = (tid >= off) ? buf[tid - off] : 0;
    __syncthreads();
    buf[tid] += t;
    __syncthreads();
  }
  if (i < n) rowptr[i] = buf[tid] - v;  // local exclusive
  if (tid == 255) blockSums[blockIdx.x] = buf[255];
}

__global__ void k_scan_sums(int* __restrict__ bs, int nb) {
  __shared__ int buf[256];
  int tid = threadIdx.x;
  int v = (tid < nb) ? bs[tid] : 0;
  buf[tid] = v;
  __syncthreads();
#pragma unroll
  for (int off = 1; off < 256; off <<= 1) {
    int t = (tid >= off) ? buf[tid - off] : 0;
    __syncthreads();
    buf[tid] += t;
    __syncthreads();
  }
  if (tid < nb) bs[tid] = buf[tid] - v;  // exclusive
  if (tid == 255) bs[nb] = buf[255];     // total
}

__global__ void k_scan_add(int* __restrict__ rowptr, const int* __restrict__ bs, int n, int nb) {
  int i = blockIdx.x * blockDim.x + threadIdx.x;
  if (i < n) rowptr[i] += bs[i >> 8];
  else if (i == n) rowptr[n] = bs[nb];
}

// ---------------- atomic-free CSR fill for BOTH graphs (nontemporal scatter)
__global__ void k_fill2(const int* __restrict__ eiA, const int* __restrict__ eiP,
                        const float* __restrict__ pea, int E, int n,
                        const int* __restrict__ rowptrA, const int* __restrict__ rowptrP,
                        const int* __restrict__ posA, const int* __restrict__ posP,
                        int* __restrict__ srcsA, int2* __restrict__ packP,
                        const float* __restrict__ scal) {
  int tot = E + n;
  int tot2 = 2 * tot;
  float meanea = scal[0] / (float)E;
  for (int i = blockIdx.x * blockDim.x + threadIdx.x; i < tot2; i += gridDim.x * blockDim.x) {
    if (i < tot) {
      int e = i;
      int s, d;
      if (e < E) { s = eiA[e]; d = eiA[(size_t)E + e]; }
      else { s = d = e - E; }
      int slot = rowptrA[d] + posA[e];
      __builtin_nontemporal_store(s, &srcsA[slot]);
    } else {
      int e = i - tot;
      int s, d;
      float ev;
      if (e < E) { s = eiP[e]; d = eiP[(size_t)E + e]; ev = pea[e]; }
      else { s = d = e - E; ev = meanea; }
      int slot = rowptrP[d] + posP[e];
      unsigned long long u =
          ((unsigned long long)__float_as_uint(ev) << 32) | (unsigned int)s;
      __builtin_nontemporal_store(u, (unsigned long long*)&packP[slot]);
    }
  }
}

// ---------------- W transpose+fp16 convert: Wt[n][k] = (f16)W[k][n], x2 arrays
__global__ void k_wconv(const float* __restrict__ W1, const float* __restrict__ W2,
                        _Float16* __restrict__ Wt1, _Float16* __restrict__ Wt2,
                        int K, int N) {
  int tot = K * N;
  for (int i = blockIdx.x * blockDim.x + threadIdx.x; i < 2 * tot;
       i += gridDim.x * blockDim.x) {
    bool second = i >= tot;
    int e = second ? i - tot : i;
    int k = e / N, n = e % N;
    float v = (second ? W2 : W1)[e];
    (second ? Wt2 : Wt1)[n * K + k] = (_Float16)v;
  }
}

// ---------------- layer-1 dual MFMA GEMM: C1=(f16)x@W1, C2=(f16)x@pW1.
// LDS-free: one wave owns a 16-row strip x NCOLS cols x both branches.
// A frag loaded f32 from x + cvt in-reg; B frags 16B loads from fp16 Wt (L2).
template <int NCOLS>
__global__ __launch_bounds__(256) void mfma_dual(const float* __restrict__ A,
                                                 const _Float16* __restrict__ Wt1,
                                                 const _Float16* __restrict__ Wt2,
                                                 __half* __restrict__ C1,
                                                 __half* __restrict__ C2,
                                                 int M, int K) {
  constexpr int NB = NCOLS / 16;
  int wid = (int)((blockIdx.x * blockDim.x + threadIdx.x) >> 6);
  int lane = threadIdx.x & 63;
  int rowTile = wid * 16;
  if (rowTile >= M) return;
  int l15 = lane & 15;
  int kb = lane >> 4;
  const float* ap = A + (size_t)(rowTile + l15) * K + kb * 8;
  const _Float16* b1p = Wt1 + (size_t)l15 * K + kb * 8;
  const _Float16* b2p = Wt2 + (size_t)l15 * K + kb * 8;
  f32x4v acc1[NB], acc2[NB];
#pragma unroll
  for (int nb = 0; nb < NB; ++nb) {
    f32x4v z = {0.f, 0.f, 0.f, 0.f};
    acc1[nb] = z;
    acc2[nb] = z;
  }
  for (int k0 = 0; k0 < K; k0 += 32) {
    float4 a0 = *(const float4*)(ap + k0);
    float4 a1 = *(const float4*)(ap + k0 + 4);
    f16x8v af;
    af[0] = (_Float16)a0.x; af[1] = (_Float16)a0.y;
    af[2] = (_Float16)a0.z; af[3] = (_Float16)a0.w;
    af[4] = (_Float16)a1.x; af[5] = (_Float16)a1.y;
    af[6] = (_Float16)a1.z; af[7] = (_Float16)a1.w;
#pragma unroll
    for (int nb = 0; nb < NB; ++nb) {
      f16x8v b1 = *(const f16x8v*)(b1p + (size_t)nb * 16 * K + k0);
      f16x8v b2 = *(const f16x8v*)(b2p + (size_t)nb * 16 * K + k0);
      acc1[nb] = __builtin_amdgcn_mfma_f32_16x16x32_f16(af, b1, acc1[nb], 0, 0, 0);
      acc2[nb] = __builtin_amdgcn_mfma_f32_16x16x32_f16(af, b2, acc2[nb], 0, 0, 0);
    }
  }
  // C/D frag: col = lane&15, row = (lane>>4)*4 + reg (16x16x32 family)
  int orow = rowTile + kb * 4;
#pragma unroll
  for (int nb = 0; nb < NB; ++nb) {
    int oc = nb * 16 + l15;
#pragma unroll
    for (int j = 0; j < 4; ++j) {
      C1[(size_t)(orow + j) * NCOLS + oc] = __float2half(acc1[nb][j]);
      C2[(size_t)(orow + j) * NCOLS + oc] = __float2half(acc2[nb][j]);
    }
  }
}

// ---------------- layer-2 pair GEMM (blockIdx.z selects branch), fp16 out
template <int BM, int BN, int BK, int TM, int TN>
__global__ __launch_bounds__(256) void gemm_pair_h(const float* __restrict__ A0,
                                                   const float* __restrict__ A1,
                                                   const float* __restrict__ B0,
                                                   const float* __restrict__ B1,
                                                   __half* __restrict__ C0,
                                                   __half* __restrict__ C1,
                                                   int M, int N, int K) {
  const float* A = blockIdx.z ? A1 : A0;
  const float* B = blockIdx.z ? B1 : B0;
  __half* C = blockIdx.z ? C1 : C0;
  __shared__ float As[BK][BM + 4];
  __shared__ float Bs[BK][BN + 4];
  constexpr int TX = BN / TN;
  const int tid = threadIdx.x;
  const int tx = tid % TX;
  const int ty = tid / TX;
  const int rowBase = blockIdx.x * BM;
  const int colBase = blockIdx.y * BN;
  float acc[TM][TN] = {};
  constexpr int A4 = (BM * BK / 4) / 256;
  constexpr int B4 = (BN * BK / 4) / 256;
  for (int k0 = 0; k0 < K; k0 += BK) {
#pragma unroll
    for (int it = 0; it < A4; ++it) {
      int idx = it * 256 + tid;
      int row = idx / (BK / 4);
      int cv = (idx % (BK / 4)) * 4;
      int gr = rowBase + row;
      float4 v = make_float4(0.f, 0.f, 0.f, 0.f);
      if (gr < M) v = *(const float4*)(A + (size_t)gr * K + k0 + cv);
      As[cv + 0][row] = v.x;
      As[cv + 1][row] = v.y;
      As[cv + 2][row] = v.z;
      As[cv + 3][row] = v.w;
    }
#pragma unroll
    for (int it = 0; it < B4; ++it) {
      int idx = it * 256 + tid;
      int r = idx / (BN / 4);
      int c = (idx % (BN / 4)) * 4;
      *(float4*)&Bs[r][c] = *(const float4*)(B + (size_t)(k0 + r) * N + colBase + c);
    }
    __syncthreads();
#pragma unroll
    for (int kk = 0; kk < BK; ++kk) {
      float a[TM], b[TN];
#pragma unroll
      for (int i = 0; i < TM; i += 4) *(float4*)&a[i] = *(const float4*)&As[kk][ty * TM + i];
#pragma unroll
      for (int j = 0; j < TN; j += 4) *(float4*)&b[j] = *(const float4*)&Bs[kk][tx * TN + j];
#pragma unroll
      for (int i = 0; i < TM; ++i)
#pragma unroll
        for (int j = 0; j < TN; ++j) acc[i][j] = fmaf(a[i], b[j], acc[i][j]);
    }
    __syncthreads();
  }
#pragma unroll
  for (int i = 0; i < TM; ++i) {
    int gr = rowBase + ty * TM + i;
    if (gr < M) {
      __half* cp = C + (size_t)gr * N + colBase + tx * TN;
#pragma unroll
      for (int j = 0; j < TN; j += 2)
        *(__half2*)&cp[j] = __floats2half2_rn(acc[i][j], acc[i][j + 1]);
    }
  }
}

// ---------------- per-node att dots for BOTH branches (fp16 h)
template <int DIM>
__global__ void k_node_dots2(const __half* __restrict__ hA, const __half* __restrict__ hP,
                             const float* __restrict__ vaA, const float* __restrict__ vbA,
                             const float* __restrict__ vaP, const float* __restrict__ vbP,
                             float* __restrict__ asA, float* __restrict__ adA,
                             float* __restrict__ asP, float* __restrict__ adP, int n) {
  int wid = (blockIdx.x * blockDim.x + threadIdx.x) >> 6;
  int lane = threadIdx.x & 63;
  if (wid >= n) return;
  bool isP = blockIdx.y != 0;
  const __half* h = isP ? hP : hA;
  const float* va = isP ? vaP : vaA;
  const float* vb = isP ? vbP : vbA;
  float* oa = isP ? asP : asA;
  float* ob = isP ? adP : adA;
  const __half* hr = h + (size_t)wid * DIM;
  float pa = 0.f, pb = 0.f;
#pragma unroll
  for (int v = 0; v < DIM / 64; ++v) {
    float xv = __half2float(hr[lane + 64 * v]);
    pa += xv * va[lane + 64 * v];
    pb += xv * vb[lane + 64 * v];
  }
  pa = waveReduceSum(pa);
  pb = waveReduceSum(pb);
  if (lane == 0) { oa[wid] = pa; ob[wid] = pb; }
}

DEV float leaky02(float a) { return a > 0.f ? a : 0.2f * a; }
DEV float expw(float a) { return __expf(fminf(a, 80.f)); }

// ---------------- GAT aggregation, BOTH branches, chunked lane-parallel
// alpha + shuffle-broadcast fp16 gather. One wave per dst node.
template <int DIM>
__global__ void k_gat_agg2(const __half* __restrict__ hA, const __half* __restrict__ hP,
                           const int* __restrict__ rowptrA, const int* __restrict__ rowptrP,
                           const int* __restrict__ srcsA, const int2* __restrict__ packP,
                           const float* __restrict__ scal, int scal_idx,
                           const float* __restrict__ asA, const float* __restrict__ adA,
                           const float* __restrict__ asP, const float* __restrict__ adP,
                           const float* __restrict__ biasA, const float* __restrict__ biasP,
                           const float* __restrict__ paA, const float* __restrict__ paP,
                           float* __restrict__ outA, float* __restrict__ outP, int n) {
  int wid = (blockIdx.x * blockDim.x + threadIdx.x) >> 6;
  int lane = threadIdx.x & 63;
  if (wid >= n) return;
  bool isP = blockIdx.y != 0;
  const char* hb = (const char*)(isP ? hP : hA);
  const int* rowptr = isP ? rowptrP : rowptrA;
  const float* as_ = isP ? asP : asA;
  const float* bias = isP ? biasP : biasA;
  float* outp = isP ? outP : outA;
  float adv = (isP ? adP : adA)[wid];
  float pa = (isP ? paP : paA)[0];
  float c = isP ? scal[scal_idx] : 0.f;
  int e0 = rowptr[wid], e1 = rowptr[wid + 1];
  float ssum = 0.f;
  float accx = 0.f, accy = 0.f;
  const unsigned lb = (DIM == 128) ? ((unsigned)lane << 2) : ((unsigned)lane << 1);
  for (int base = e0; base < e1; base += 64) {
    // phase 1: one edge per lane — coalesced loads, lane-parallel exp
    int ee = base + lane;
    float w = 0.f;
    int s = 0;
    if (ee < e1) {
      float a;
      if (isP) {
        int2 p = packP[ee];
        s = p.x;
        a = c * __int_as_float(p.y);
      } else {
        s = srcsA[ee];
        a = 0.f;
      }
      a += as_[s] + adv;
      w = expw(leaky02(a));
    }
    ssum += w;
    // phase 2: broadcast (w, s) and gather fp16 h rows (dim-parallel)
    int cnt = min(64, e1 - base);
    int j = 0;
    for (; j + 4 <= cnt; j += 4) {
      float w0 = __shfl(w, j), w1 = __shfl(w, j + 1);
      float w2 = __shfl(w, j + 2), w3 = __shfl(w, j + 3);
      int s0 = __shfl(s, j), s1 = __shfl(s, j + 1);
      int s2 = __shfl(s, j + 2), s3 = __shfl(s, j + 3);
      if constexpr (DIM == 128) {
        __half2 v0 = *(const __half2*)(hb + (((unsigned)s0 << 8) + lb));
        __half2 v1 = *(const __half2*)(hb + (((unsigned)s1 << 8) + lb));
        __half2 v2 = *(const __half2*)(hb + (((unsigned)s2 << 8) + lb));
        __half2 v3 = *(const __half2*)(hb + (((unsigned)s3 << 8) + lb));
        float2 f0 = __half22float2(v0), f1 = __half22float2(v1);
        float2 f2 = __half22float2(v2), f3 = __half22float2(v3);
        accx += w0 * f0.x + w1 * f1.x + w2 * f2.x + w3 * f3.x;
        accy += w0 * f0.y + w1 * f1.y + w2 * f2.y + w3 * f3.y;
      } else {
        float f0 = __half2float(*(const __half*)(hb + (((unsigned)s0 << 7) + lb)));
        float f1 = __half2float(*(const __half*)(hb + (((unsigned)s1 << 7) + lb)));
        float f2 = __half2float(*(const __half*)(hb + (((unsigned)s2 << 7) + lb)));
        float f3 = __half2float(*(const __half*)(hb + (((unsigned)s3 << 7) + lb)));
        accx += w0 * f0 + w1 * f1 + w2 * f2 + w3 * f3;
      }
    }
    for (; j < cnt; ++j) {
      float wj = __shfl(w, j);
      int sj = __shfl(s, j);
      if constexpr (DIM == 128) {
        float2 f = __half22float2(*(const __half2*)(hb + (((unsigned)sj << 8) + lb)));
        accx += wj * f.x;
        accy += wj * f.y;
      } else {
        accx += wj * __half2float(*(const __half*)(hb + (((unsigned)sj << 7) + lb)));
      }
    }
  }
  ssum = waveReduceSum(ssum);
  float inv = 1.f / (ssum + 1e-16f);
  if constexpr (DIM == 128) {
    float2 bv = ((const float2*)bias)[lane];
    float ox = accx * inv + bv.x;
    float oy = accy * inv + bv.y;
    ox = ox >= 0.f ? ox : pa * ox;
    oy = oy >= 0.f ? oy : pa * oy;
    ((float2*)(outp + (size_t)wid * 128))[lane] = make_float2(ox, oy);
  } else {
    float o = accx * inv + bias[lane];
    o = o >= 0.f ? o : pa * o;
    outp[(size_t)wid * 64 + lane] = o;
  }
}

// ---------------- fusion softmax + classifier: one wave per node
__global__ void k_fuse(const float* __restrict__ lout, const float* __restrict__ gout,
                       const float* __restrict__ attn_w, const float* __restrict__ attn_b,
                       const float* __restrict__ clf_w, const float* __restrict__ clf_b,
                       float* __restrict__ out, int n) {
  int wid = (blockIdx.x * blockDim.x + threadIdx.x) >> 6;
  int lane = threadIdx.x & 63;
  if (wid >= n) return;
  float l = lout[(size_t)wid * 64 + lane];
  float g = gout[(size_t)wid * 64 + lane];
  float aw = attn_w[lane];
  float s0 = waveReduceSum(l * aw) + attn_b[0];
  float s1 = waveReduceSum(g * aw) + attn_b[0];
  float mx = fmaxf(s0, s1);
  float e0 = __expf(s0 - mx), e1 = __expf(s1 - mx);
  float inv = 1.f / (e0 + e1);
  float w0 = e0 * inv, w1 = e1 * inv;
  float emb = w0 * l + w1 * g;
  out[(size_t)wid * 64 + lane] = emb;
  float p[NCLS];
#pragma unroll
  for (int cc = 0; cc < NCLS; ++cc) p[cc] = emb * clf_w[lane * NCLS + cc];
#pragma unroll
  for (int off = 32; off; off >>= 1)
#pragma unroll
    for (int cc = 0; cc < NCLS; ++cc) p[cc] += __shfl_xor(p[cc], off);
  if (lane < NCLS) {
    float val = 0.f;
#pragma unroll
    for (int cc = 0; cc < NCLS; ++cc)
      if (lane == cc) val = p[cc];
    out[(size_t)n * 64 + (size_t)wid * NCLS + lane] = val + clf_b[lane];
  }
}

extern "C" void kernel_launch(void* const* d_in, const int* in_sizes, int n_in,
                              void* d_out, int out_size, void* d_ws, size_t ws_size,
                              hipStream_t stream) {
  const float* x         = (const float*)d_in[0];
  const int*   ei        = (const int*)d_in[1];
  const int*   pei       = (const int*)d_in[2];
  const float* pea       = (const float*)d_in[3];
  const float* W1        = (const float*)d_in[4];
  const float* att_src1  = (const float*)d_in[5];
  const float* att_dst1  = (const float*)d_in[6];
  const float* b1        = (const float*)d_in[7];
  const float* W2        = (const float*)d_in[8];
  const float* att_src2  = (const float*)d_in[9];
  const float* att_dst2  = (const float*)d_in[10];
  const float* b2        = (const float*)d_in[11];
  const float* prelu_a   = (const float*)d_in[12];
  const float* pW1       = (const float*)d_in[13];
  const float* patt_src1 = (const float*)d_in[14];
  const float* patt_dst1 = (const float*)d_in[15];
  const float* pWe1      = (const float*)d_in[16];
  const float* patt_e1   = (const float*)d_in[17];
  const float* pb1       = (const float*)d_in[18];
  const float* pW2       = (const float*)d_in[19];
  const float* patt_src2 = (const float*)d_in[20];
  const float* patt_dst2 = (const float*)d_in[21];
  const float* pWe2      = (const float*)d_in[22];
  const float* patt_e2   = (const float*)d_in[23];
  const float* pb2       = (const float*)d_in[24];
  const float* pprelu_a  = (const float*)d_in[25];
  const float* attn_w    = (const float*)d_in[26];
  const float* attn_b    = (const float*)d_in[27];
  const float* clf_w     = (const float*)d_in[28];
  const float* clf_b     = (const float*)d_in[29];
  float* out = (float*)d_out;

  const int N = in_sizes[0] / D_IN;
  const int E = in_sizes[1] / 2;
  const int Etot = E + N;

  // ---- workspace: byte bump allocator, 256B-aligned blocks
  char* wsp = (char*)d_ws;
  size_t used = 0;
  auto alloc = [&](size_t bytes) {
    char* p = wsp + used;
    used += (bytes + 255) & ~(size_t)255;
    return p;
  };
  __half* h1a_h = (__half*)alloc((size_t)N * H1c * 2);
  __half* h1p_h = (__half*)alloc((size_t)N * H1c * 2);
  float*  f1a   = (float*)alloc((size_t)N * H1c * 4);
  float*  g1p   = (float*)alloc((size_t)N * H1c * 4);
  __half* h2a_h = (__half*)alloc((size_t)N * H2c * 2);
  __half* h2p_h = (__half*)alloc((size_t)N * H2c * 2);
  float*  as_a  = (float*)alloc((size_t)N * 4);
  float*  ad_a  = (float*)alloc((size_t)N * 4);
  float*  as_p  = (float*)alloc((size_t)N * 4);
  float*  ad_p  = (float*)alloc((size_t)N * 4);
  float*  scal  = (float*)alloc(64);
  int*    rowptrA = (int*)alloc((size_t)(N + 1) * 4);
  int*    rowptrP = (int*)alloc((size_t)(N + 1) * 4);
  int*    countsA = (int*)alloc((size_t)N * 4);
  int*    countsP = (int*)alloc((size_t)N * 4);
  int*    blockSums = (int*)alloc(513 * 4);
  int*    srcsA = (int*)alloc((size_t)Etot * 4);
  int2*   packP = (int2*)alloc((size_t)Etot * 8);
  _Float16* Wt1 = (_Float16*)alloc((size_t)D_IN * H1c * 2);
  _Float16* Wt2 = (_Float16*)alloc((size_t)D_IN * H1c * 2);
  // overlays: pos arrays live in f1a/g1p (written only after fill);
  // l_out/g_out live in h1 half-buffers (dead after layer-1 agg/dots).
  int* posA = (int*)f1a;
  int* posP = posA + Etot;
  float* l_out = (float*)h1a_h;  // N*H2 floats == N*H1c halves bytes
  float* g_out = (float*)h1p_h;
  if (used > ws_size) return;  // would corrupt; fail loudly (output stays zero)

  hipMemsetAsync(countsA, 0, sizeof(int) * (size_t)N, stream);
  hipMemsetAsync(countsP, 0, sizeof(int) * (size_t)N, stream);
  hipMemsetAsync(scal, 0, 64, stream);

  const int GS = 2048;
  k_sum<<<1024, 256, 0, stream>>>(pea, E, scal);
  k_edge_coef<<<1, 64, 0, stream>>>(pWe1, patt_e1, pWe2, patt_e2, scal);
  k_wconv<<<64, 256, 0, stream>>>(W1, pW1, Wt1, Wt2, D_IN, H1c);

  // CSR build for both graphs
  k_count2<<<GS, 256, 0, stream>>>(ei, pei, E, N, countsA, countsP, posA, posP);
  int nb = (N + 255) / 256;
  int scanAddBlocks = (N + 1 + 255) / 256;
  k_scan_block<<<nb, 256, 0, stream>>>(countsA, N, rowptrA, blockSums);
  k_scan_sums<<<1, 256, 0, stream>>>(blockSums, nb);
  k_scan_add<<<scanAddBlocks, 256, 0, stream>>>(rowptrA, blockSums, N, nb);
  k_scan_block<<<nb, 256, 0, stream>>>(countsP, N, rowptrP, blockSums);
  k_scan_sums<<<1, 256, 0, stream>>>(blockSums, nb);
  k_scan_add<<<scanAddBlocks, 256, 0, stream>>>(rowptrP, blockSums, N, nb);
  k_fill2<<<GS, 256, 0, stream>>>(ei, pei, pea, E, N, rowptrA, rowptrP, posA, posP,
                                  srcsA, packP, scal);

  // layer 1: MFMA dual GEMM (one wave per 16-row strip, no LDS/barriers)
  int nwaves = (N + 15) / 16;
  int mblocks = (nwaves * 64 + 255) / 256;
  mfma_dual<H1c><<<mblocks, 256, 0, stream>>>(x, Wt1, Wt2, h1a_h, h1p_h, N, D_IN);
  int gw = (N + 3) / 4;
  dim3 gd(gw, 2);
  k_node_dots2<H1c><<<gd, 256, 0, stream>>>(h1a_h, h1p_h, att_src1, att_dst1, patt_src1,
                                            patt_dst1, as_a, ad_a, as_p, ad_p, N);
  k_gat_agg2<H1c><<<gd, 256, 0, stream>>>(h1a_h, h1p_h, rowptrA, rowptrP, srcsA, packP,
                                          scal, 1, as_a, ad_a, as_p, ad_p, b1, pb1,
                                          prelu_a, pprelu_a, f1a, g1p, N);

  // layer 2 (both branches in one dispatch via blockIdx.z)
  dim3 g2((N + 63) / 64, H2c / 64, 2);
  gemm_pair_h<64, 64, 32, 4, 4><<<g2, 256, 0, stream>>>(f1a, g1p, W2, pW2, h2a_h, h2p_h,
                                                        N, H2c, H1c);
  k_node_dots2<H2c><<<gd, 256, 0, stream>>>(h2a_h, h2p_h, att_src2, att_dst2, patt_src2,
                                            patt_dst2, as_a, ad_a, as_p, ad_p, N);
  k_gat_agg2<H2c><<<gd, 256, 0, stream>>>(h2a_h, h2p_h, rowptrA, rowptrP, srcsA, packP,
                                          scal, 2, as_a, ad_a, as_p, ad_p, b2, pb2,
                                          prelu_a, pprelu_a, l_out, g_out, N);

  // fusion + classifier
  k_fuse<<<gw, 256, 0, stream>>>(l_out, g_out, attn_w, attn_b, clf_w, clf_b, out, N);
}